// Round 1
// baseline (1336.475 us; speedup 1.0000x reference)
//
#include <hip/hip_runtime.h>
#include <cmath>

// Problem constants (B=2, L=2048, D=1024, H=16, Dh=64), all fp32.
#define D_MODEL  1024
#define NHEADS   16
#define DHEAD    64
#define BATCH    2
#define SEQ      2048
#define MROWS    (BATCH * SEQ)          // 4096 rows for the projection GEMMs
#define HALF_DH  (DHEAD / 2)            // 32 rotary frequencies

// ---------------------------------------------------------------------------
// K0: RoPE cos/sin tables, [SEQ][32] each. Precomputed once per call so the
// GEMM epilogue does table lookups instead of sinf/cosf per element.
// ---------------------------------------------------------------------------
__global__ void rope_table_kernel(float* __restrict__ cosT, float* __restrict__ sinT) {
    int idx = blockIdx.x * blockDim.x + threadIdx.x;
    if (idx >= SEQ * HALF_DH) return;
    int l = idx >> 5;          // sequence position
    int j = idx & 31;          // frequency index
    // inv_freq = 10000^(-2j/64) computed in fp32 like the reference
    float inv = powf(10000.0f, -(float)(2 * j) / (float)DHEAD);
    float ang = (float)l * inv;
    cosT[idx] = cosf(ang);
    sinT[idx] = sinf(ang);
}

// ---------------------------------------------------------------------------
// K1: tiled fp32 GEMM  C[4096,1024] = X @ W + bias, 64x64 tile, BK=16,
// 256 threads, 4x4 micro-tile per thread.
// MODE 0: store C row-major to out            (output projection)
// MODE 1: store to [B,H,L,Dh] with RoPE       (q, k)
// MODE 2: store to [B,H,L,Dh] without RoPE    (v)
// ---------------------------------------------------------------------------
template<int MODE>
__global__ __launch_bounds__(256)
void gemm_proj_kernel(const float* __restrict__ X, const float* __restrict__ W,
                      const float* __restrict__ bias,
                      const float* __restrict__ cosT, const float* __restrict__ sinT,
                      float* __restrict__ out)
{
    __shared__ float As[64][17];   // [row][k]  +1 pad
    __shared__ float Bs[16][65];   // [k][col]  +1 pad
    const int tid = threadIdx.x;
    const int tx = tid & 15, ty = tid >> 4;
    const int bm = blockIdx.x * 64;     // row tile  (4096/64 = 64 tiles)
    const int bn = blockIdx.y * 64;     // col tile  (1024/64 = 16 tiles)

    float acc[4][4] = {{0.f}};

    for (int k0 = 0; k0 < D_MODEL; k0 += 16) {
        // stage A: 64x16, coalesced (16 consecutive k per row)
        {
            int c = tid & 15, r0 = tid >> 4;        // 16 rows per pass
            #pragma unroll
            for (int p = 0; p < 4; ++p)
                As[r0 + 16 * p][c] = X[(size_t)(bm + r0 + 16 * p) * D_MODEL + k0 + c];
        }
        // stage B: 16x64, coalesced (64 consecutive cols per row)
        {
            int c = tid & 63, r0 = tid >> 6;        // 4 rows per pass
            #pragma unroll
            for (int p = 0; p < 4; ++p)
                Bs[r0 + 4 * p][c] = W[(size_t)(k0 + r0 + 4 * p) * D_MODEL + bn + c];
        }
        __syncthreads();
        #pragma unroll
        for (int kk = 0; kk < 16; ++kk) {
            float a[4], b[4];
            #pragma unroll
            for (int i = 0; i < 4; ++i) a[i] = As[ty + 16 * i][kk];
            #pragma unroll
            for (int j = 0; j < 4; ++j) b[j] = Bs[kk][tx + 16 * j];
            #pragma unroll
            for (int i = 0; i < 4; ++i)
                #pragma unroll
                for (int j = 0; j < 4; ++j)
                    acc[i][j] = fmaf(a[i], b[j], acc[i][j]);
        }
        __syncthreads();
    }

    // epilogue: bias (+ RoPE) + store
    const int h = bn >> 6;   // head (BN=64 is head-aligned)
    #pragma unroll
    for (int i = 0; i < 4; ++i) {
        const int m = bm + ty + 16 * i;     // global row
        const int b = m >> 11;              // /SEQ
        const int l = m & (SEQ - 1);
        #pragma unroll
        for (int j = 0; j < 4; ++j)
            acc[i][j] += bias[bn + tx + 16 * j];

        if (MODE == 1) {
            // cols owned: d = tx+16j. j in {0,1} -> d<32 pairs with j+2 (d+32).
            #pragma unroll
            for (int j = 0; j < 2; ++j) {
                int d = tx + 16 * j;                       // < 32
                float c = cosT[l * HALF_DH + d];
                float s = sinT[l * HALF_DH + d];
                float lo = acc[i][j], hi = acc[i][j + 2];
                acc[i][j]     = lo * c - hi * s;           // q[d]*cos - q[d+32]*sin
                acc[i][j + 2] = hi * c + lo * s;           // q[d+32]*cos + q[d]*sin
            }
        }

        if (MODE == 0) {
            float* dst = out + (size_t)m * D_MODEL + bn;
            #pragma unroll
            for (int j = 0; j < 4; ++j) dst[tx + 16 * j] = acc[i][j];
        } else {
            // [B,H,L,Dh]
            float* dst = out + (((size_t)b * NHEADS + h) * SEQ + l) * DHEAD;
            #pragma unroll
            for (int j = 0; j < 4; ++j) dst[tx + 16 * j] = acc[i][j];
        }
    }
}

// ---------------------------------------------------------------------------
// K2: flash-style attention. One block = 64 q-rows of one (b,h).
// Online softmax over 32 k-tiles of 64. O written directly in [B,L,D].
// ---------------------------------------------------------------------------
__global__ __launch_bounds__(256)
void attn_fwd_kernel(const float* __restrict__ Q, const float* __restrict__ K,
                     const float* __restrict__ V, float* __restrict__ O)
{
    __shared__ float Qs[64][65];
    __shared__ float Ks[64][65];
    __shared__ float Vs[64][65];
    __shared__ float Ps[64][65];
    __shared__ float red[64][4];
    __shared__ float mRow[64], rRow[64], mState[64], lState[64];

    const int tid = threadIdx.x;
    const int tx = tid & 15, ty = tid >> 4;
    const int bh = blockIdx.y;                 // 0..31  (b*16 + h)
    const int q0 = blockIdx.x * 64;
    const float scale = 0.125f;                // Dh^-0.5 = 1/8

    const float* Qb = Q + (size_t)bh * SEQ * DHEAD;
    const float* Kb = K + (size_t)bh * SEQ * DHEAD;
    const float* Vb = V + (size_t)bh * SEQ * DHEAD;

    // load Q tile (64x64), coalesced
    {
        int c = tid & 63, r0 = tid >> 6;
        #pragma unroll
        for (int p = 0; p < 16; ++p)
            Qs[r0 + 4 * p][c] = Qb[(size_t)(q0 + r0 + 4 * p) * DHEAD + c];
    }
    if (tid < 64) { mState[tid] = -1e30f; lState[tid] = 0.f; }

    float accO[4][4] = {{0.f}};
    const int rr = tid >> 2, qq = tid & 3;     // row-reduction role: 4 threads/row

    for (int kt = 0; kt < SEQ; kt += 64) {
        __syncthreads();    // Ks/Vs/Ps reuse safe (also covers Q/state init)
        {
            int c = tid & 63, r0 = tid >> 6;
            #pragma unroll
            for (int p = 0; p < 16; ++p) {
                Ks[r0 + 4 * p][c] = Kb[(size_t)(kt + r0 + 4 * p) * DHEAD + c];
                Vs[r0 + 4 * p][c] = Vb[(size_t)(kt + r0 + 4 * p) * DHEAD + c];
            }
        }
        __syncthreads();

        // S = scale * Q K^T  (64x64x64), 4x4 per thread
        float s[4][4] = {{0.f}};
        #pragma unroll
        for (int d = 0; d < 64; ++d) {
            float a[4], b[4];
            #pragma unroll
            for (int i = 0; i < 4; ++i) a[i] = Qs[ty + 16 * i][d];
            #pragma unroll
            for (int j = 0; j < 4; ++j) b[j] = Ks[tx + 16 * j][d];
            #pragma unroll
            for (int i = 0; i < 4; ++i)
                #pragma unroll
                for (int j = 0; j < 4; ++j)
                    s[i][j] = fmaf(a[i], b[j], s[i][j]);
        }
        #pragma unroll
        for (int i = 0; i < 4; ++i)
            #pragma unroll
            for (int j = 0; j < 4; ++j)
                Ps[ty + 16 * i][tx + 16 * j] = s[i][j] * scale;
        __syncthreads();

        // row max partials (4 threads x 16 elems per row)
        float mx = -1e30f;
        #pragma unroll
        for (int c = 0; c < 16; ++c) mx = fmaxf(mx, Ps[rr][qq * 16 + c]);
        red[rr][qq] = mx;
        __syncthreads();
        if (qq == 0) {
            float mnew = fmaxf(fmaxf(red[rr][0], red[rr][1]),
                               fmaxf(red[rr][2], red[rr][3]));
            mnew = fmaxf(mnew, mState[rr]);
            mRow[rr] = mnew;
            rRow[rr] = expf(mState[rr] - mnew);
        }
        __syncthreads();

        // P = exp(S - m_new), partial row sums
        float mnew = mRow[rr];
        float ps = 0.f;
        #pragma unroll
        for (int c = 0; c < 16; ++c) {
            float p = expf(Ps[rr][qq * 16 + c] - mnew);
            Ps[rr][qq * 16 + c] = p;
            ps += p;
        }
        red[rr][qq] = ps;
        __syncthreads();
        if (qq == 0) {
            lState[rr] = lState[rr] * rRow[rr]
                       + red[rr][0] + red[rr][1] + red[rr][2] + red[rr][3];
            mState[rr] = mnew;
        }
        __syncthreads();

        // O = O*rescale + P V
        #pragma unroll
        for (int i = 0; i < 4; ++i) {
            float rsc = rRow[ty + 16 * i];
            #pragma unroll
            for (int j = 0; j < 4; ++j) accO[i][j] *= rsc;
        }
        #pragma unroll
        for (int d = 0; d < 64; ++d) {
            float a[4], b[4];
            #pragma unroll
            for (int i = 0; i < 4; ++i) a[i] = Ps[ty + 16 * i][d];
            #pragma unroll
            for (int j = 0; j < 4; ++j) b[j] = Vs[d][tx + 16 * j];
            #pragma unroll
            for (int i = 0; i < 4; ++i)
                #pragma unroll
                for (int j = 0; j < 4; ++j)
                    accO[i][j] = fmaf(a[i], b[j], accO[i][j]);
        }
    }

    // epilogue: O /= l, write [B,L,D]
    const int b = bh >> 4, h = bh & 15;
    #pragma unroll
    for (int i = 0; i < 4; ++i) {
        const int l = q0 + ty + 16 * i;
        const float inv = 1.0f / lState[ty + 16 * i];
        float* dst = O + ((size_t)b * SEQ + l) * D_MODEL + h * DHEAD;
        #pragma unroll
        for (int j = 0; j < 4; ++j) dst[tx + 16 * j] = accO[i][j] * inv;
    }
}

// ---------------------------------------------------------------------------
extern "C" void kernel_launch(void* const* d_in, const int* in_sizes, int n_in,
                              void* d_out, int out_size, void* d_ws, size_t ws_size,
                              hipStream_t stream)
{
    const float* x  = (const float*)d_in[0];
    const float* Wq = (const float*)d_in[1];
    const float* bq = (const float*)d_in[2];
    const float* Wk = (const float*)d_in[3];
    const float* bk = (const float*)d_in[4];
    const float* Wv = (const float*)d_in[5];
    const float* bv = (const float*)d_in[6];
    const float* Wo = (const float*)d_in[7];
    const float* bo = (const float*)d_in[8];
    float* out = (float*)d_out;

    // workspace carve-up (fp32): rope tables + q/k/v [B,H,L,Dh] + attn out [B,L,D]
    float* ws   = (float*)d_ws;
    float* cosT = ws;                                   // 2048*32 = 65536
    float* sinT = cosT + SEQ * HALF_DH;                 // 65536
    float* qb   = sinT + SEQ * HALF_DH;                 // 4 Mi floats
    float* kb   = qb + (size_t)MROWS * D_MODEL;
    float* vb   = kb + (size_t)MROWS * D_MODEL;
    float* ob   = vb + (size_t)MROWS * D_MODEL;         // attn output, [B,L,D]

    // K0: RoPE tables
    {
        int n = SEQ * HALF_DH;
        rope_table_kernel<<<(n + 255) / 256, 256, 0, stream>>>(cosT, sinT);
    }

    // K1 x3: projections (q,k with RoPE -> [B,H,L,Dh]; v plain -> [B,H,L,Dh])
    dim3 ggrid(MROWS / 64, D_MODEL / 64);
    gemm_proj_kernel<1><<<ggrid, 256, 0, stream>>>(x, Wq, bq, cosT, sinT, qb);
    gemm_proj_kernel<1><<<ggrid, 256, 0, stream>>>(x, Wk, bk, cosT, sinT, kb);
    gemm_proj_kernel<2><<<ggrid, 256, 0, stream>>>(x, Wv, bv, cosT, sinT, vb);

    // K2: flash attention -> ob [B,L,D]
    dim3 agrid(SEQ / 64, BATCH * NHEADS);
    attn_fwd_kernel<<<agrid, 256, 0, stream>>>(qb, kb, vb, ob);

    // K3: output projection -> d_out
    gemm_proj_kernel<0><<<ggrid, 256, 0, stream>>>(ob, Wo, bo, cosT, sinT, out);
}

// Round 2
// 217.296 us; speedup vs baseline: 6.1505x; 6.1505x over previous
//
#include <hip/hip_runtime.h>
#include <cmath>

#define D_MODEL  1024
#define NHEADS   16
#define DHEAD    64
#define BATCH    2
#define SEQ      2048
#define MROWS    (BATCH * SEQ)
#define HALF_DH  32

typedef __attribute__((ext_vector_type(8))) short short8;   // 8 bf16 = 4 VGPRs (MFMA A/B frag)
typedef __attribute__((ext_vector_type(4))) float f32x4;    // MFMA C/D frag

// round-to-nearest-even fp32 -> bf16 bits
__device__ __forceinline__ unsigned short f2bf(float f) {
    unsigned int u = __float_as_uint(f);
    u += 0x7fffu + ((u >> 16) & 1u);
    return (unsigned short)(u >> 16);
}

// async global->LDS, 16B per lane; LDS dest = wave-uniform base + lane*16
__device__ __forceinline__ void gload_lds16(const void* g, void* l) {
    __builtin_amdgcn_global_load_lds(
        (const __attribute__((address_space(1))) unsigned int*)g,
        (__attribute__((address_space(3))) unsigned int*)l,
        16, 0, 0);
}

// ---------------------------------------------------------------------------
// K0: RoPE cos/sin tables [SEQ][32] fp32
// ---------------------------------------------------------------------------
__global__ void rope_table_kernel(float* __restrict__ cosT, float* __restrict__ sinT) {
    int idx = blockIdx.x * blockDim.x + threadIdx.x;
    if (idx >= SEQ * HALF_DH) return;
    int l = idx >> 5;
    int j = idx & 31;
    float inv = powf(10000.0f, -(float)(2 * j) / (float)DHEAD);
    float ang = (float)l * inv;
    cosT[idx] = cosf(ang);
    sinT[idx] = sinf(ang);
}

// ---------------------------------------------------------------------------
// K1: fp32 -> bf16 elementwise (x). n/4 threads, exact grid.
// ---------------------------------------------------------------------------
__global__ __launch_bounds__(256)
void convert_bf16_kernel(const float* __restrict__ in, unsigned short* __restrict__ out) {
    int i = blockIdx.x * 256 + threadIdx.x;
    float4 v = ((const float4*)in)[i];
    ushort4 o;
    o.x = f2bf(v.x); o.y = f2bf(v.y); o.z = f2bf(v.z); o.w = f2bf(v.w);
    ((ushort4*)out)[i] = o;
}

// ---------------------------------------------------------------------------
// K2: W[k][n] fp32 -> Wt[n][k] bf16 (transpose+convert), 64x64 LDS tiles
// ---------------------------------------------------------------------------
__global__ __launch_bounds__(256)
void wtrans_kernel(const float* __restrict__ W, unsigned short* __restrict__ Wt) {
    __shared__ unsigned short T[64][68];
    const int k0 = blockIdx.x * 64, n0 = blockIdx.y * 64;
    const int t = threadIdx.x, r = t >> 4, cq = t & 15;
    #pragma unroll
    for (int p = 0; p < 4; ++p) {
        int k = r + 16 * p;
        float4 v = *(const float4*)&W[(size_t)(k0 + k) * D_MODEL + n0 + cq * 4];
        T[cq * 4 + 0][k] = f2bf(v.x);
        T[cq * 4 + 1][k] = f2bf(v.y);
        T[cq * 4 + 2][k] = f2bf(v.z);
        T[cq * 4 + 3][k] = f2bf(v.w);
    }
    __syncthreads();
    #pragma unroll
    for (int p = 0; p < 4; ++p) {
        int n = r + 16 * p;
        ushort4 o;
        o.x = T[n][cq * 4 + 0]; o.y = T[n][cq * 4 + 1];
        o.z = T[n][cq * 4 + 2]; o.w = T[n][cq * 4 + 3];
        *(ushort4*)&Wt[(size_t)(n0 + n) * D_MODEL + k0 + cq * 4] = o;
    }
}

// ---------------------------------------------------------------------------
// K3: MFMA projection GEMM. C[4096,1024] = A(bf16) @ Bt^T + bias.
// A: [4096][1024] bf16 row-major. Bt: [n][k] bf16 (pre-transposed weight).
// BM=128 BN=64 BK=64, 256 thr = 4 waves, wave w owns rows w*32..+32.
// LDS rows are 128B (64 bf16), 16B-block XOR swizzle: blk ^= (row&7).
// MODE 0: bias+RoPE -> bf16 [b,h,l,d] | MODE 1: bias -> bf16 [b,h,l,d]
// MODE 2: bias -> fp32 row-major [m][1024]
// ---------------------------------------------------------------------------
template<int MODE>
__global__ __launch_bounds__(256)
void proj_mfma_kernel(const unsigned short* __restrict__ A, const unsigned short* __restrict__ Bt,
                      const float* __restrict__ bias, const float* __restrict__ cosT,
                      const float* __restrict__ sinT, void* __restrict__ outp)
{
    __shared__ unsigned short As[128 * 64];
    __shared__ unsigned short Bs[64 * 64];
    const int tid = threadIdx.x;
    const int w = tid >> 6, ln = tid & 63;
    const int c = ln & 15, g = ln >> 4;
    const int bm = blockIdx.x * 128, bn = blockIdx.y * 64;
    const int srow = ln >> 3, sblk = ln & 7;

    f32x4 acc[2][4];
    #pragma unroll
    for (int mi = 0; mi < 2; ++mi)
        #pragma unroll
        for (int ni = 0; ni < 4; ++ni) acc[mi][ni] = (f32x4){0.f, 0.f, 0.f, 0.f};

    for (int k0 = 0; k0 < D_MODEL; k0 += 64) {
        __syncthreads();
        // stage A tile 128x64 (16 chunks of 1024B), B tile 64x64 (8 chunks)
        #pragma unroll
        for (int i = 0; i < 4; ++i) {
            int chunk = w * 4 + i;
            int row = chunk * 8 + srow;
            int gcol = (sblk ^ (row & 7)) * 8;
            gload_lds16(&A[(size_t)(bm + row) * D_MODEL + k0 + gcol], &As[chunk * 512]);
        }
        #pragma unroll
        for (int i = 0; i < 2; ++i) {
            int chunk = w * 2 + i;
            int row = chunk * 8 + srow;
            int gcol = (sblk ^ (row & 7)) * 8;
            gload_lds16(&Bt[(size_t)(bn + row) * D_MODEL + k0 + gcol], &Bs[chunk * 512]);
        }
        __syncthreads();   // compiler drains vmcnt before s_barrier

        #pragma unroll
        for (int ks = 0; ks < 2; ++ks) {
            const int koff = (ks * 32 + g * 8) ^ ((c & 7) * 8);
            short8 af[2];
            #pragma unroll
            for (int mi = 0; mi < 2; ++mi)
                af[mi] = *(const short8*)&As[(w * 32 + mi * 16 + c) * 64 + koff];
            #pragma unroll
            for (int ni = 0; ni < 4; ++ni) {
                short8 bfr = *(const short8*)&Bs[(ni * 16 + c) * 64 + koff];
                #pragma unroll
                for (int mi = 0; mi < 2; ++mi)
                    acc[mi][ni] = __builtin_amdgcn_mfma_f32_16x16x32_bf16(af[mi], bfr, acc[mi][ni], 0, 0, 0);
            }
        }
    }

    // epilogue: C row = bm + w*32 + mi*16 + g*4 + r, col = bn + ni*16 + c
    float bv[4];
    #pragma unroll
    for (int ni = 0; ni < 4; ++ni) bv[ni] = bias[bn + ni * 16 + c];

    #pragma unroll
    for (int mi = 0; mi < 2; ++mi) {
        #pragma unroll
        for (int r = 0; r < 4; ++r) {
            const int m = bm + w * 32 + mi * 16 + g * 4 + r;
            float v[4];
            #pragma unroll
            for (int ni = 0; ni < 4; ++ni) v[ni] = acc[mi][ni][r] + bv[ni];
            if (MODE == 2) {
                float* out = (float*)outp;
                #pragma unroll
                for (int ni = 0; ni < 4; ++ni)
                    out[(size_t)m * D_MODEL + bn + ni * 16 + c] = v[ni];
            } else {
                const int b = m >> 11, ll = m & (SEQ - 1);
                if (MODE == 0) {
                    #pragma unroll
                    for (int ni = 0; ni < 2; ++ni) {
                        int d = ni * 16 + c;          // < 32
                        float co = cosT[ll * HALF_DH + d];
                        float si = sinT[ll * HALF_DH + d];
                        float lo = v[ni], hi = v[ni + 2];
                        v[ni]     = lo * co - hi * si;
                        v[ni + 2] = hi * co + lo * si;
                    }
                }
                const int h = blockIdx.y;             // BN == DHEAD
                unsigned short* dst = (unsigned short*)outp
                    + ((size_t)(b * NHEADS + h) * SEQ + ll) * DHEAD;
                #pragma unroll
                for (int ni = 0; ni < 4; ++ni) dst[ni * 16 + c] = f2bf(v[ni]);
            }
        }
    }
}

// ---------------------------------------------------------------------------
// K4: V [bh][l][64] bf16 -> Vt [bh][64][l] bf16 (per-head transpose)
// ---------------------------------------------------------------------------
__global__ __launch_bounds__(256)
void vtrans_kernel(const unsigned short* __restrict__ V, unsigned short* __restrict__ Vt) {
    __shared__ unsigned short T[64][68];
    const int bh = blockIdx.y, l0 = blockIdx.x * 64;
    const int t = threadIdx.x, r = t >> 4, cq = t & 15;
    const unsigned short* Vb = V + (size_t)bh * SEQ * DHEAD;
    #pragma unroll
    for (int p = 0; p < 4; ++p) {
        int ll = r + 16 * p;
        ushort4 v = *(const ushort4*)&Vb[(size_t)(l0 + ll) * DHEAD + cq * 4];
        T[cq * 4 + 0][ll] = v.x; T[cq * 4 + 1][ll] = v.y;
        T[cq * 4 + 2][ll] = v.z; T[cq * 4 + 3][ll] = v.w;
    }
    __syncthreads();
    unsigned short* Vo = Vt + (size_t)bh * DHEAD * SEQ;
    #pragma unroll
    for (int p = 0; p < 4; ++p) {
        int d = r + 16 * p;
        ushort4 o;
        o.x = T[d][cq * 4 + 0]; o.y = T[d][cq * 4 + 1];
        o.z = T[d][cq * 4 + 2]; o.w = T[d][cq * 4 + 3];
        *(ushort4*)&Vo[(size_t)d * SEQ + l0 + cq * 4] = o;
    }
}

// ---------------------------------------------------------------------------
// K5: MFMA flash attention. Block = 64 q-rows of one (b,h); 4 waves, wave w
// owns q-rows w*16..+16. K-tiles of 64. Q frags in registers; K/Vt staged via
// global_load_lds into XOR-swizzled LDS; online softmax in registers via
// __shfl_xor over the 16 col-lanes; P -> LDS (bf16, swizzled) -> PV MFMA.
// O written bf16 to [B,L,D].
// ---------------------------------------------------------------------------
__global__ __launch_bounds__(256)
void attn_mfma_kernel(const unsigned short* __restrict__ Q, const unsigned short* __restrict__ K,
                      const unsigned short* __restrict__ Vt, unsigned short* __restrict__ O)
{
    __shared__ unsigned short Ks[64 * 64];
    __shared__ unsigned short Vs[64 * 64];   // Vt tile: [d][k] (k along the 64-tile)
    __shared__ unsigned short Ps[64 * 64];
    const int tid = threadIdx.x;
    const int w = tid >> 6, ln = tid & 63;
    const int c = ln & 15, g = ln >> 4;
    const int bh = blockIdx.y;
    const int q0 = blockIdx.x * 64;
    const float sc = 0.125f * 1.44269504088896340736f;   // scale * log2(e)
    const int srow = ln >> 3, sblk = ln & 7;

    const unsigned short* Qb = Q  + (size_t)bh * SEQ * DHEAD;
    const unsigned short* Kb = K  + (size_t)bh * SEQ * DHEAD;
    const unsigned short* Vb = Vt + (size_t)bh * DHEAD * SEQ;

    // Q fragments (A-operand): row = q0 + w*16 + (lane&15), k = ks*32 + g*8
    short8 qf[2];
    {
        const size_t qr = (size_t)(q0 + w * 16 + c) * DHEAD;
        qf[0] = *(const short8*)&Qb[qr + g * 8];
        qf[1] = *(const short8*)&Qb[qr + 32 + g * 8];
    }

    f32x4 accO[4];
    #pragma unroll
    for (int df = 0; df < 4; ++df) accO[df] = (f32x4){0.f, 0.f, 0.f, 0.f};
    float mst[4], lst[4];
    #pragma unroll
    for (int r = 0; r < 4; ++r) { mst[r] = -1e30f; lst[r] = 0.f; }

    for (int kt = 0; kt < SEQ; kt += 64) {
        __syncthreads();   // prior tile's LDS reads complete
        #pragma unroll
        for (int i = 0; i < 2; ++i) {
            int chunk = w * 2 + i;
            int row = chunk * 8 + srow;
            int gcol = (sblk ^ (row & 7)) * 8;
            gload_lds16(&Kb[(size_t)(kt + row) * DHEAD + gcol], &Ks[chunk * 512]);
            gload_lds16(&Vb[(size_t)row * SEQ + kt + gcol],     &Vs[chunk * 512]);
        }
        __syncthreads();   // vmcnt drained before barrier

        // S = Q K^T : A=Q frag, B from Ks (K rows are the transposed-B layout)
        f32x4 s[4];
        #pragma unroll
        for (int nf = 0; nf < 4; ++nf) s[nf] = (f32x4){0.f, 0.f, 0.f, 0.f};
        #pragma unroll
        for (int ks = 0; ks < 2; ++ks) {
            const int koff = (ks * 32 + g * 8) ^ ((c & 7) * 8);
            #pragma unroll
            for (int nf = 0; nf < 4; ++nf) {
                short8 kf = *(const short8*)&Ks[(nf * 16 + c) * 64 + koff];
                s[nf] = __builtin_amdgcn_mfma_f32_16x16x32_bf16(qf[ks], kf, s[nf], 0, 0, 0);
            }
        }

        // online softmax; lane holds rows (g*4+r), cols (nf*16+c)
        float mx[4];
        #pragma unroll
        for (int r = 0; r < 4; ++r)
            mx[r] = fmaxf(fmaxf(s[0][r], s[1][r]), fmaxf(s[2][r], s[3][r]));
        #pragma unroll
        for (int st = 1; st < 16; st <<= 1)
            #pragma unroll
            for (int r = 0; r < 4; ++r) mx[r] = fmaxf(mx[r], __shfl_xor(mx[r], st));
        float resc[4];
        #pragma unroll
        for (int r = 0; r < 4; ++r) {
            float mn = fmaxf(mst[r], mx[r]);
            resc[r] = exp2f((mst[r] - mn) * sc);
            mst[r] = mn;
        }
        float rs[4] = {0.f, 0.f, 0.f, 0.f};
        #pragma unroll
        for (int nf = 0; nf < 4; ++nf) {
            #pragma unroll
            for (int r = 0; r < 4; ++r) {
                float pv = exp2f((s[nf][r] - mst[r]) * sc);
                rs[r] += pv;
                int q = w * 16 + g * 4 + r;
                int cb = (2 * (c + 16 * nf)) ^ ((q & 7) << 4);
                Ps[q * 64 + (cb >> 1)] = f2bf(pv);
            }
        }
        #pragma unroll
        for (int st = 1; st < 16; st <<= 1)
            #pragma unroll
            for (int r = 0; r < 4; ++r) rs[r] += __shfl_xor(rs[r], st);
        #pragma unroll
        for (int r = 0; r < 4; ++r) lst[r] = lst[r] * resc[r] + rs[r];
        #pragma unroll
        for (int df = 0; df < 4; ++df) {
            f32x4 t = accO[df];
            #pragma unroll
            for (int r = 0; r < 4; ++r) t[r] *= resc[r];
            accO[df] = t;
        }

        // PV: A = P (own wave's rows, no barrier needed), B from Vs [d][k]
        #pragma unroll
        for (int ks = 0; ks < 2; ++ks) {
            const int koff = (ks * 32 + g * 8) ^ ((c & 7) * 8);
            short8 pa = *(const short8*)&Ps[(w * 16 + c) * 64 + koff];
            #pragma unroll
            for (int df = 0; df < 4; ++df) {
                short8 vf = *(const short8*)&Vs[(df * 16 + c) * 64 + koff];
                accO[df] = __builtin_amdgcn_mfma_f32_16x16x32_bf16(pa, vf, accO[df], 0, 0, 0);
            }
        }
    }

    // epilogue: O[q][d] /= l, bf16 to [B,L,D]
    const int b = bh >> 4, h = bh & 15;
    float inv[4];
    #pragma unroll
    for (int r = 0; r < 4; ++r) inv[r] = 1.0f / lst[r];
    #pragma unroll
    for (int df = 0; df < 4; ++df) {
        #pragma unroll
        for (int r = 0; r < 4; ++r) {
            int q = q0 + w * 16 + g * 4 + r;
            O[((size_t)(b * SEQ + q)) * D_MODEL + h * DHEAD + df * 16 + c]
                = f2bf(accO[df][r] * inv[r]);
        }
    }
}

// ---------------------------------------------------------------------------
extern "C" void kernel_launch(void* const* d_in, const int* in_sizes, int n_in,
                              void* d_out, int out_size, void* d_ws, size_t ws_size,
                              hipStream_t stream)
{
    const float* x  = (const float*)d_in[0];
    const float* Wq = (const float*)d_in[1];
    const float* bq = (const float*)d_in[2];
    const float* Wk = (const float*)d_in[3];
    const float* bk = (const float*)d_in[4];
    const float* Wv = (const float*)d_in[5];
    const float* bv = (const float*)d_in[6];
    const float* Wo = (const float*)d_in[7];
    const float* bo = (const float*)d_in[8];

    // workspace carve-up (~56.5 MB)
    float* cosT = (float*)d_ws;
    float* sinT = cosT + SEQ * HALF_DH;
    unsigned short* xb  = (unsigned short*)(sinT + SEQ * HALF_DH);
    unsigned short* wqT = xb  + (size_t)MROWS * D_MODEL;
    unsigned short* wkT = wqT + (size_t)D_MODEL * D_MODEL;
    unsigned short* wvT = wkT + (size_t)D_MODEL * D_MODEL;
    unsigned short* woT = wvT + (size_t)D_MODEL * D_MODEL;
    unsigned short* qb  = woT + (size_t)D_MODEL * D_MODEL;
    unsigned short* kb  = qb  + (size_t)MROWS * D_MODEL;
    unsigned short* vb  = kb  + (size_t)MROWS * D_MODEL;
    unsigned short* vtb = vb  + (size_t)MROWS * D_MODEL;
    unsigned short* ob  = vtb + (size_t)MROWS * D_MODEL;

    // K0: RoPE tables
    rope_table_kernel<<<(SEQ * HALF_DH + 255) / 256, 256, 0, stream>>>(cosT, sinT);

    // K1: x -> bf16
    convert_bf16_kernel<<<(MROWS * D_MODEL / 4) / 256, 256, 0, stream>>>(x, xb);

    // K2: weights -> transposed bf16
    dim3 wgrid(D_MODEL / 64, D_MODEL / 64);
    wtrans_kernel<<<wgrid, 256, 0, stream>>>(Wq, wqT);
    wtrans_kernel<<<wgrid, 256, 0, stream>>>(Wk, wkT);
    wtrans_kernel<<<wgrid, 256, 0, stream>>>(Wv, wvT);
    wtrans_kernel<<<wgrid, 256, 0, stream>>>(Wo, woT);

    // K3: projections
    dim3 pgrid(MROWS / 128, D_MODEL / 64);
    proj_mfma_kernel<0><<<pgrid, 256, 0, stream>>>(xb, wqT, bq, cosT, sinT, qb);
    proj_mfma_kernel<0><<<pgrid, 256, 0, stream>>>(xb, wkT, bk, cosT, sinT, kb);
    proj_mfma_kernel<1><<<pgrid, 256, 0, stream>>>(xb, wvT, bv, cosT, sinT, vb);

    // K4: V transpose -> [bh][d][l]
    dim3 vgrid(SEQ / 64, BATCH * NHEADS);
    vtrans_kernel<<<vgrid, 256, 0, stream>>>(vb, vtb);

    // K5: flash attention -> ob bf16 [B,L,D]
    dim3 agrid(SEQ / 64, BATCH * NHEADS);
    attn_mfma_kernel<<<agrid, 256, 0, stream>>>(qb, kb, vtb, ob);

    // K6: output projection -> d_out fp32
    proj_mfma_kernel<2><<<pgrid, 256, 0, stream>>>(ob, woT, bo, cosT, sinT, d_out);
}

// Round 4
// 198.076 us; speedup vs baseline: 6.7473x; 1.0970x over previous
//
#include <hip/hip_runtime.h>
#include <cmath>

#define D_MODEL  1024
#define NHEADS   16
#define DHEAD    64
#define BATCH    2
#define SEQ      2048
#define MROWS    (BATCH * SEQ)
#define HALF_DH  32

typedef __attribute__((ext_vector_type(8))) short short8;   // 8 bf16 = 4 VGPRs (MFMA A/B frag)
typedef __attribute__((ext_vector_type(4))) float f32x4;    // MFMA C/D frag

// round-to-nearest-even fp32 -> bf16 bits (epilogue use; not in hot loops)
__device__ __forceinline__ unsigned short f2bf(float f) {
    unsigned int u = __float_as_uint(f);
    u += 0x7fffu + ((u >> 16) & 1u);
    return (unsigned short)(u >> 16);
}

// async global->LDS, 16B per lane; LDS dest = wave-uniform base + lane*16
__device__ __forceinline__ void gload_lds16(const void* g, void* l) {
    __builtin_amdgcn_global_load_lds(
        (const __attribute__((address_space(1))) unsigned int*)g,
        (__attribute__((address_space(3))) unsigned int*)l,
        16, 0, 0);
}

// ---------------------------------------------------------------------------
// K0: RoPE cos/sin tables [SEQ][32] fp32
// ---------------------------------------------------------------------------
__global__ void rope_table_kernel(float* __restrict__ cosT, float* __restrict__ sinT) {
    int idx = blockIdx.x * blockDim.x + threadIdx.x;
    if (idx >= SEQ * HALF_DH) return;
    int l = idx >> 5;
    int j = idx & 31;
    float inv = powf(10000.0f, -(float)(2 * j) / (float)DHEAD);
    float ang = (float)l * inv;
    cosT[idx] = cosf(ang);
    sinT[idx] = sinf(ang);
}

// ---------------------------------------------------------------------------
// K1: fp32 -> bf16 elementwise (x)
// ---------------------------------------------------------------------------
__global__ __launch_bounds__(256)
void convert_bf16_kernel(const float* __restrict__ in, unsigned short* __restrict__ out) {
    int i = blockIdx.x * 256 + threadIdx.x;
    float4 v = ((const float4*)in)[i];
    ushort4 o;
    o.x = f2bf(v.x); o.y = f2bf(v.y); o.z = f2bf(v.z); o.w = f2bf(v.w);
    ((ushort4*)out)[i] = o;
}

// ---------------------------------------------------------------------------
// K2: W[k][n] fp32 -> Wt[n][k] bf16 (transpose+convert)
// ---------------------------------------------------------------------------
__global__ __launch_bounds__(256)
void wtrans_kernel(const float* __restrict__ W, unsigned short* __restrict__ Wt) {
    __shared__ unsigned short T[64][68];
    const int k0 = blockIdx.x * 64, n0 = blockIdx.y * 64;
    const int t = threadIdx.x, r = t >> 4, cq = t & 15;
    #pragma unroll
    for (int p = 0; p < 4; ++p) {
        int k = r + 16 * p;
        float4 v = *(const float4*)&W[(size_t)(k0 + k) * D_MODEL + n0 + cq * 4];
        T[cq * 4 + 0][k] = f2bf(v.x);
        T[cq * 4 + 1][k] = f2bf(v.y);
        T[cq * 4 + 2][k] = f2bf(v.z);
        T[cq * 4 + 3][k] = f2bf(v.w);
    }
    __syncthreads();
    #pragma unroll
    for (int p = 0; p < 4; ++p) {
        int n = r + 16 * p;
        ushort4 o;
        o.x = T[n][cq * 4 + 0]; o.y = T[n][cq * 4 + 1];
        o.z = T[n][cq * 4 + 2]; o.w = T[n][cq * 4 + 3];
        *(ushort4*)&Wt[(size_t)(n0 + n) * D_MODEL + k0 + cq * 4] = o;
    }
}

// ---------------------------------------------------------------------------
// K3: MFMA projection GEMM (unchanged, passing).
// ---------------------------------------------------------------------------
template<int MODE>
__global__ __launch_bounds__(256)
void proj_mfma_kernel(const unsigned short* __restrict__ A, const unsigned short* __restrict__ Bt,
                      const float* __restrict__ bias, const float* __restrict__ cosT,
                      const float* __restrict__ sinT, void* __restrict__ outp)
{
    __shared__ unsigned short As[128 * 64];
    __shared__ unsigned short Bs[64 * 64];
    const int tid = threadIdx.x;
    const int w = tid >> 6, ln = tid & 63;
    const int c = ln & 15, g = ln >> 4;
    const int bm = blockIdx.x * 128, bn = blockIdx.y * 64;
    const int srow = ln >> 3, sblk = ln & 7;

    f32x4 acc[2][4];
    #pragma unroll
    for (int mi = 0; mi < 2; ++mi)
        #pragma unroll
        for (int ni = 0; ni < 4; ++ni) acc[mi][ni] = (f32x4){0.f, 0.f, 0.f, 0.f};

    for (int k0 = 0; k0 < D_MODEL; k0 += 64) {
        __syncthreads();
        #pragma unroll
        for (int i = 0; i < 4; ++i) {
            int chunk = w * 4 + i;
            int row = chunk * 8 + srow;
            int gcol = (sblk ^ (row & 7)) * 8;
            gload_lds16(&A[(size_t)(bm + row) * D_MODEL + k0 + gcol], &As[chunk * 512]);
        }
        #pragma unroll
        for (int i = 0; i < 2; ++i) {
            int chunk = w * 2 + i;
            int row = chunk * 8 + srow;
            int gcol = (sblk ^ (row & 7)) * 8;
            gload_lds16(&Bt[(size_t)(bn + row) * D_MODEL + k0 + gcol], &Bs[chunk * 512]);
        }
        __syncthreads();

        #pragma unroll
        for (int ks = 0; ks < 2; ++ks) {
            const int koff = (ks * 32 + g * 8) ^ ((c & 7) * 8);
            short8 af[2];
            #pragma unroll
            for (int mi = 0; mi < 2; ++mi)
                af[mi] = *(const short8*)&As[(w * 32 + mi * 16 + c) * 64 + koff];
            #pragma unroll
            for (int ni = 0; ni < 4; ++ni) {
                short8 bfr = *(const short8*)&Bs[(ni * 16 + c) * 64 + koff];
                #pragma unroll
                for (int mi = 0; mi < 2; ++mi)
                    acc[mi][ni] = __builtin_amdgcn_mfma_f32_16x16x32_bf16(af[mi], bfr, acc[mi][ni], 0, 0, 0);
            }
        }
    }

    float bv[4];
    #pragma unroll
    for (int ni = 0; ni < 4; ++ni) bv[ni] = bias[bn + ni * 16 + c];

    #pragma unroll
    for (int mi = 0; mi < 2; ++mi) {
        #pragma unroll
        for (int r = 0; r < 4; ++r) {
            const int m = bm + w * 32 + mi * 16 + g * 4 + r;
            float v[4];
            #pragma unroll
            for (int ni = 0; ni < 4; ++ni) v[ni] = acc[mi][ni][r] + bv[ni];
            if (MODE == 2) {
                float* out = (float*)outp;
                #pragma unroll
                for (int ni = 0; ni < 4; ++ni)
                    out[(size_t)m * D_MODEL + bn + ni * 16 + c] = v[ni];
            } else {
                const int b = m >> 11, ll = m & (SEQ - 1);
                if (MODE == 0) {
                    #pragma unroll
                    for (int ni = 0; ni < 2; ++ni) {
                        int d = ni * 16 + c;
                        float co = cosT[ll * HALF_DH + d];
                        float si = sinT[ll * HALF_DH + d];
                        float lo = v[ni], hi = v[ni + 2];
                        v[ni]     = lo * co - hi * si;
                        v[ni + 2] = hi * co + lo * si;
                    }
                }
                const int h = blockIdx.y;
                unsigned short* dst = (unsigned short*)outp
                    + ((size_t)(b * NHEADS + h) * SEQ + ll) * DHEAD;
                #pragma unroll
                for (int ni = 0; ni < 4; ++ni) dst[ni * 16 + c] = f2bf(v[ni]);
            }
        }
    }
}

// ---------------------------------------------------------------------------
// K4: V [bh][l][64] bf16 -> Vt [bh][64][l] bf16
// ---------------------------------------------------------------------------
__global__ __launch_bounds__(256)
void vtrans_kernel(const unsigned short* __restrict__ V, unsigned short* __restrict__ Vt) {
    __shared__ unsigned short T[64][68];
    const int bh = blockIdx.y, l0 = blockIdx.x * 64;
    const int t = threadIdx.x, r = t >> 4, cq = t & 15;
    const unsigned short* Vb = V + (size_t)bh * SEQ * DHEAD;
    #pragma unroll
    for (int p = 0; p < 4; ++p) {
        int ll = r + 16 * p;
        ushort4 v = *(const ushort4*)&Vb[(size_t)(l0 + ll) * DHEAD + cq * 4];
        T[cq * 4 + 0][ll] = v.x; T[cq * 4 + 1][ll] = v.y;
        T[cq * 4 + 2][ll] = v.z; T[cq * 4 + 3][ll] = v.w;
    }
    __syncthreads();
    unsigned short* Vo = Vt + (size_t)bh * DHEAD * SEQ;
    #pragma unroll
    for (int p = 0; p < 4; ++p) {
        int d = r + 16 * p;
        ushort4 o;
        o.x = T[d][cq * 4 + 0]; o.y = T[d][cq * 4 + 1];
        o.z = T[d][cq * 4 + 2]; o.w = T[d][cq * 4 + 3];
        *(ushort4*)&Vo[(size_t)d * SEQ + l0 + cq * 4] = o;
    }
}

// ---------------------------------------------------------------------------
// K5: MFMA flash attention. ONLINE ROW-MAX restored (R2 numerics: P <= 1;
// the R3 fixed-shift variant failed validation at 16x threshold).
// Kept from R3: 2-phase double-buffered K/V staging (one barrier/tile),
// v_cvt_pk_bf16_f32 P->bf16, ones-MFMA row sums (accL rescaled with accO).
// ---------------------------------------------------------------------------
__global__ __launch_bounds__(256)
void attn_mfma_kernel(const unsigned short* __restrict__ Q, const unsigned short* __restrict__ K,
                      const unsigned short* __restrict__ Vt, unsigned short* __restrict__ O)
{
    __shared__ unsigned short Ks[2][64 * 64];
    __shared__ unsigned short Vs[2][64 * 64];
    __shared__ unsigned short Ps[64 * 64];
    const int tid = threadIdx.x;
    const int w = tid >> 6, ln = tid & 63;
    const int c = ln & 15, g = ln >> 4;
    const int bh = blockIdx.y;
    const int q0 = blockIdx.x * 64;
    const float SC = 0.125f * 1.44269504088896340736f;   // scale * log2(e)
    const int srow = ln >> 3, sblk = ln & 7;

    const unsigned short* Qb = Q  + (size_t)bh * SEQ * DHEAD;
    const unsigned short* Kb = K  + (size_t)bh * SEQ * DHEAD;
    const unsigned short* Vb = Vt + (size_t)bh * DHEAD * SEQ;

    // Q fragments (A-operand): row = q0 + w*16 + c, k = ks*32 + g*8
    short8 qf[2];
    {
        const size_t qr = (size_t)(q0 + w * 16 + c) * DHEAD;
        qf[0] = *(const short8*)&Qb[qr + g * 8];
        qf[1] = *(const short8*)&Qb[qr + 32 + g * 8];
    }

    // constant all-ones bf16 B-fragment (1.0 = 0x3F80) for row sums
    short8 onesF;
    #pragma unroll
    for (int i = 0; i < 8; ++i) onesF[i] = (short)0x3F80;

    f32x4 accO[4];
    #pragma unroll
    for (int df = 0; df < 4; ++df) accO[df] = (f32x4){0.f, 0.f, 0.f, 0.f};
    f32x4 accL = (f32x4){0.f, 0.f, 0.f, 0.f};
    float mst[4];
    #pragma unroll
    for (int r = 0; r < 4; ++r) mst[r] = -1e30f;

    // prologue: stage tile 0 into buf 0
    #pragma unroll
    for (int i = 0; i < 2; ++i) {
        int chunk = w * 2 + i;
        int row = chunk * 8 + srow;
        int gcol = (sblk ^ (row & 7)) * 8;
        gload_lds16(&Kb[(size_t)row * DHEAD + gcol], &Ks[0][chunk * 512]);
        gload_lds16(&Vb[(size_t)row * SEQ + gcol],   &Vs[0][chunk * 512]);
    }
    __syncthreads();

    int cur = 0;
    for (int kt = 0; kt < SEQ; kt += 64) {
        // stage NEXT tile into buf^1 (in flight during compute)
        if (kt + 64 < SEQ) {
            #pragma unroll
            for (int i = 0; i < 2; ++i) {
                int chunk = w * 2 + i;
                int row = chunk * 8 + srow;
                int gcol = (sblk ^ (row & 7)) * 8;
                gload_lds16(&Kb[(size_t)(kt + 64 + row) * DHEAD + gcol], &Ks[cur ^ 1][chunk * 512]);
                gload_lds16(&Vb[(size_t)row * SEQ + kt + 64 + gcol],     &Vs[cur ^ 1][chunk * 512]);
            }
        }

        // S = Q K^T
        f32x4 s[4];
        #pragma unroll
        for (int nf = 0; nf < 4; ++nf) s[nf] = (f32x4){0.f, 0.f, 0.f, 0.f};
        #pragma unroll
        for (int ks = 0; ks < 2; ++ks) {
            const int koff = (ks * 32 + g * 8) ^ ((c & 7) * 8);
            #pragma unroll
            for (int nf = 0; nf < 4; ++nf) {
                short8 kf = *(const short8*)&Ks[cur][(nf * 16 + c) * 64 + koff];
                s[nf] = __builtin_amdgcn_mfma_f32_16x16x32_bf16(qf[ks], kf, s[nf], 0, 0, 0);
            }
        }

        // online row max across this tile's 64 cols (lane group of 16 shares a row set)
        float mx[4];
        #pragma unroll
        for (int r = 0; r < 4; ++r)
            mx[r] = fmaxf(fmaxf(s[0][r], s[1][r]), fmaxf(s[2][r], s[3][r]));
        #pragma unroll
        for (int st = 1; st < 16; st <<= 1)
            #pragma unroll
            for (int r = 0; r < 4; ++r) mx[r] = fmaxf(mx[r], __shfl_xor(mx[r], st));
        float resc[4];
        #pragma unroll
        for (int r = 0; r < 4; ++r) {
            float mn = fmaxf(mst[r], mx[r]);
            resc[r] = exp2f((mst[r] - mn) * SC);
            mst[r] = mn;
        }

        // P = exp2((S - m)*SC) -> bf16 -> Ps (swizzled); rows g*4+r, cols nf*16+c
        float px[4][4];
        #pragma unroll
        for (int nf = 0; nf < 4; ++nf)
            #pragma unroll
            for (int r = 0; r < 4; ++r)
                px[nf][r] = exp2f((s[nf][r] - mst[r]) * SC);
        #pragma unroll
        for (int r = 0; r < 4; ++r) {
            const int q = w * 16 + g * 4 + r;
            const int rowbase = q * 64;
            const int sw = (q & 7) * 8;
            #pragma unroll
            for (int np = 0; np < 2; ++np) {
                unsigned int pk;
                asm("v_cvt_pk_bf16_f32 %0, %1, %2"
                    : "=v"(pk) : "v"(px[2 * np][r]), "v"(px[2 * np + 1][r]));
                Ps[rowbase + ((32 * np + c) ^ sw)]      = (unsigned short)pk;
                Ps[rowbase + ((32 * np + 16 + c) ^ sw)] = (unsigned short)(pk >> 16);
            }
        }

        // rescale running accumulators (O and L) by exp(m_old - m_new)
        #pragma unroll
        for (int df = 0; df < 4; ++df) {
            f32x4 t = accO[df];
            #pragma unroll
            for (int r = 0; r < 4; ++r) t[r] *= resc[r];
            accO[df] = t;
        }
        #pragma unroll
        for (int r = 0; r < 4; ++r) accL[r] *= resc[r];

        // PV + ones row-sum: A = P (wave-local rows, DS in-order within wave)
        #pragma unroll
        for (int ks = 0; ks < 2; ++ks) {
            const int koff = (ks * 32 + g * 8) ^ ((c & 7) * 8);
            short8 pa = *(const short8*)&Ps[(w * 16 + c) * 64 + koff];
            accL = __builtin_amdgcn_mfma_f32_16x16x32_bf16(pa, onesF, accL, 0, 0, 0);
            #pragma unroll
            for (int df = 0; df < 4; ++df) {
                short8 vf = *(const short8*)&Vs[cur][(df * 16 + c) * 64 + koff];
                accO[df] = __builtin_amdgcn_mfma_f32_16x16x32_bf16(pa, vf, accO[df], 0, 0, 0);
            }
        }

        __syncthreads();   // drains vmcnt (next-tile stage) + all waves done with buf
        cur ^= 1;
    }

    // epilogue: O[q][d] / l, bf16 to [B,L,D]
    const int b = bh >> 4, h = bh & 15;
    float inv[4];
    #pragma unroll
    for (int r = 0; r < 4; ++r) inv[r] = 1.0f / accL[r];
    #pragma unroll
    for (int df = 0; df < 4; ++df) {
        #pragma unroll
        for (int r = 0; r < 4; ++r) {
            int q = q0 + w * 16 + g * 4 + r;
            O[((size_t)(b * SEQ + q)) * D_MODEL + h * DHEAD + df * 16 + c]
                = f2bf(accO[df][r] * inv[r]);
        }
    }
}

// ---------------------------------------------------------------------------
extern "C" void kernel_launch(void* const* d_in, const int* in_sizes, int n_in,
                              void* d_out, int out_size, void* d_ws, size_t ws_size,
                              hipStream_t stream)
{
    const float* x  = (const float*)d_in[0];
    const float* Wq = (const float*)d_in[1];
    const float* bq = (const float*)d_in[2];
    const float* Wk = (const float*)d_in[3];
    const float* bk = (const float*)d_in[4];
    const float* Wv = (const float*)d_in[5];
    const float* bv = (const float*)d_in[6];
    const float* Wo = (const float*)d_in[7];
    const float* bo = (const float*)d_in[8];

    float* cosT = (float*)d_ws;
    float* sinT = cosT + SEQ * HALF_DH;
    unsigned short* xb  = (unsigned short*)(sinT + SEQ * HALF_DH);
    unsigned short* wqT = xb  + (size_t)MROWS * D_MODEL;
    unsigned short* wkT = wqT + (size_t)D_MODEL * D_MODEL;
    unsigned short* wvT = wkT + (size_t)D_MODEL * D_MODEL;
    unsigned short* woT = wvT + (size_t)D_MODEL * D_MODEL;
    unsigned short* qb  = woT + (size_t)D_MODEL * D_MODEL;
    unsigned short* kb  = qb  + (size_t)MROWS * D_MODEL;
    unsigned short* vb  = kb  + (size_t)MROWS * D_MODEL;
    unsigned short* vtb = vb  + (size_t)MROWS * D_MODEL;
    unsigned short* ob  = vtb + (size_t)MROWS * D_MODEL;

    rope_table_kernel<<<(SEQ * HALF_DH + 255) / 256, 256, 0, stream>>>(cosT, sinT);
    convert_bf16_kernel<<<(MROWS * D_MODEL / 4) / 256, 256, 0, stream>>>(x, xb);

    dim3 wgrid(D_MODEL / 64, D_MODEL / 64);
    wtrans_kernel<<<wgrid, 256, 0, stream>>>(Wq, wqT);
    wtrans_kernel<<<wgrid, 256, 0, stream>>>(Wk, wkT);
    wtrans_kernel<<<wgrid, 256, 0, stream>>>(Wv, wvT);
    wtrans_kernel<<<wgrid, 256, 0, stream>>>(Wo, woT);

    dim3 pgrid(MROWS / 128, D_MODEL / 64);
    proj_mfma_kernel<0><<<pgrid, 256, 0, stream>>>(xb, wqT, bq, cosT, sinT, qb);
    proj_mfma_kernel<0><<<pgrid, 256, 0, stream>>>(xb, wkT, bk, cosT, sinT, kb);
    proj_mfma_kernel<1><<<pgrid, 256, 0, stream>>>(xb, wvT, bv, cosT, sinT, vb);

    dim3 vgrid(SEQ / 64, BATCH * NHEADS);
    vtrans_kernel<<<vgrid, 256, 0, stream>>>(vb, vtb);

    dim3 agrid(SEQ / 64, BATCH * NHEADS);
    attn_mfma_kernel<<<agrid, 256, 0, stream>>>(qb, kb, vtb, ob);

    proj_mfma_kernel<2><<<pgrid, 256, 0, stream>>>(ob, woT, bo, cosT, sinT, d_out);
}

// Round 5
// 168.468 us; speedup vs baseline: 7.9331x; 1.1757x over previous
//
#include <hip/hip_runtime.h>
#include <cmath>

#define D_MODEL  1024
#define NHEADS   16
#define DHEAD    64
#define BATCH    2
#define SEQ      2048
#define MROWS    (BATCH * SEQ)
#define HALF_DH  32

typedef __attribute__((ext_vector_type(8))) short short8;    // 8 bf16 = 4 VGPRs
typedef __attribute__((ext_vector_type(4))) float f32x4;     // 16x16 C/D
typedef __attribute__((ext_vector_type(16))) float f32x16;   // 32x32 C/D

#define MFMA16(A,B,C) __builtin_amdgcn_mfma_f32_16x16x32_bf16(A,B,C,0,0,0)
#define MFMA32(A,B,C) __builtin_amdgcn_mfma_f32_32x32x16_bf16(A,B,C,0,0,0)

// round-to-nearest-even fp32 -> bf16 bits
__device__ __forceinline__ unsigned short f2bf(float f) {
    unsigned int u = __float_as_uint(f);
    u += 0x7fffu + ((u >> 16) & 1u);
    return (unsigned short)(u >> 16);
}

// async global->LDS, 16B per lane; LDS dest = wave-uniform base + lane*16
__device__ __forceinline__ void gload_lds16(const void* g, void* l) {
    __builtin_amdgcn_global_load_lds(
        (const __attribute__((address_space(1))) unsigned int*)g,
        (__attribute__((address_space(3))) unsigned int*)l,
        16, 0, 0);
}

// ---------------------------------------------------------------------------
// K0: RoPE cos/sin tables [SEQ][32] fp32
// ---------------------------------------------------------------------------
__global__ void rope_table_kernel(float* __restrict__ cosT, float* __restrict__ sinT) {
    int idx = blockIdx.x * blockDim.x + threadIdx.x;
    if (idx >= SEQ * HALF_DH) return;
    int l = idx >> 5;
    int j = idx & 31;
    float inv = powf(10000.0f, -(float)(2 * j) / (float)DHEAD);
    float ang = (float)l * inv;
    cosT[idx] = cosf(ang);
    sinT[idx] = sinf(ang);
}

// ---------------------------------------------------------------------------
// K1: fp32 -> bf16 elementwise (x)
// ---------------------------------------------------------------------------
__global__ __launch_bounds__(256)
void convert_bf16_kernel(const float* __restrict__ in, unsigned short* __restrict__ out) {
    int i = blockIdx.x * 256 + threadIdx.x;
    float4 v = ((const float4*)in)[i];
    ushort4 o;
    o.x = f2bf(v.x); o.y = f2bf(v.y); o.z = f2bf(v.z); o.w = f2bf(v.w);
    ((ushort4*)out)[i] = o;
}

// ---------------------------------------------------------------------------
// K2: W[k][n] fp32 -> Wt[n][k] bf16 (transpose+convert)
// ---------------------------------------------------------------------------
__global__ __launch_bounds__(256)
void wtrans_kernel(const float* __restrict__ W, unsigned short* __restrict__ Wt) {
    __shared__ unsigned short T[64][68];
    const int k0 = blockIdx.x * 64, n0 = blockIdx.y * 64;
    const int t = threadIdx.x, r = t >> 4, cq = t & 15;
    #pragma unroll
    for (int p = 0; p < 4; ++p) {
        int k = r + 16 * p;
        float4 v = *(const float4*)&W[(size_t)(k0 + k) * D_MODEL + n0 + cq * 4];
        T[cq * 4 + 0][k] = f2bf(v.x);
        T[cq * 4 + 1][k] = f2bf(v.y);
        T[cq * 4 + 2][k] = f2bf(v.z);
        T[cq * 4 + 3][k] = f2bf(v.w);
    }
    __syncthreads();
    #pragma unroll
    for (int p = 0; p < 4; ++p) {
        int n = r + 16 * p;
        ushort4 o;
        o.x = T[n][cq * 4 + 0]; o.y = T[n][cq * 4 + 1];
        o.z = T[n][cq * 4 + 2]; o.w = T[n][cq * 4 + 3];
        *(ushort4*)&Wt[(size_t)(n0 + n) * D_MODEL + k0 + cq * 4] = o;
    }
}

// ---------------------------------------------------------------------------
// K3: MFMA projection GEMM (unchanged, passing).
// ---------------------------------------------------------------------------
template<int MODE>
__global__ __launch_bounds__(256)
void proj_mfma_kernel(const unsigned short* __restrict__ A, const unsigned short* __restrict__ Bt,
                      const float* __restrict__ bias, const float* __restrict__ cosT,
                      const float* __restrict__ sinT, void* __restrict__ outp)
{
    __shared__ unsigned short As[128 * 64];
    __shared__ unsigned short Bs[64 * 64];
    const int tid = threadIdx.x;
    const int w = tid >> 6, ln = tid & 63;
    const int c = ln & 15, g = ln >> 4;
    const int bm = blockIdx.x * 128, bn = blockIdx.y * 64;
    const int srow = ln >> 3, sblk = ln & 7;

    f32x4 acc[2][4];
    #pragma unroll
    for (int mi = 0; mi < 2; ++mi)
        #pragma unroll
        for (int ni = 0; ni < 4; ++ni) acc[mi][ni] = (f32x4){0.f, 0.f, 0.f, 0.f};

    for (int k0 = 0; k0 < D_MODEL; k0 += 64) {
        __syncthreads();
        #pragma unroll
        for (int i = 0; i < 4; ++i) {
            int chunk = w * 4 + i;
            int row = chunk * 8 + srow;
            int gcol = (sblk ^ (row & 7)) * 8;
            gload_lds16(&A[(size_t)(bm + row) * D_MODEL + k0 + gcol], &As[chunk * 512]);
        }
        #pragma unroll
        for (int i = 0; i < 2; ++i) {
            int chunk = w * 2 + i;
            int row = chunk * 8 + srow;
            int gcol = (sblk ^ (row & 7)) * 8;
            gload_lds16(&Bt[(size_t)(bn + row) * D_MODEL + k0 + gcol], &Bs[chunk * 512]);
        }
        __syncthreads();

        #pragma unroll
        for (int ks = 0; ks < 2; ++ks) {
            const int koff = (ks * 32 + g * 8) ^ ((c & 7) * 8);
            short8 af[2];
            #pragma unroll
            for (int mi = 0; mi < 2; ++mi)
                af[mi] = *(const short8*)&As[(w * 32 + mi * 16 + c) * 64 + koff];
            #pragma unroll
            for (int ni = 0; ni < 4; ++ni) {
                short8 bfr = *(const short8*)&Bs[(ni * 16 + c) * 64 + koff];
                #pragma unroll
                for (int mi = 0; mi < 2; ++mi)
                    acc[mi][ni] = MFMA16(af[mi], bfr, acc[mi][ni]);
            }
        }
    }

    float bv[4];
    #pragma unroll
    for (int ni = 0; ni < 4; ++ni) bv[ni] = bias[bn + ni * 16 + c];

    #pragma unroll
    for (int mi = 0; mi < 2; ++mi) {
        #pragma unroll
        for (int r = 0; r < 4; ++r) {
            const int m = bm + w * 32 + mi * 16 + g * 4 + r;
            float v[4];
            #pragma unroll
            for (int ni = 0; ni < 4; ++ni) v[ni] = acc[mi][ni][r] + bv[ni];
            if (MODE == 2) {
                float* out = (float*)outp;
                #pragma unroll
                for (int ni = 0; ni < 4; ++ni)
                    out[(size_t)m * D_MODEL + bn + ni * 16 + c] = v[ni];
            } else {
                const int b = m >> 11, ll = m & (SEQ - 1);
                if (MODE == 0) {
                    #pragma unroll
                    for (int ni = 0; ni < 2; ++ni) {
                        int d = ni * 16 + c;
                        float co = cosT[ll * HALF_DH + d];
                        float si = sinT[ll * HALF_DH + d];
                        float lo = v[ni], hi = v[ni + 2];
                        v[ni]     = lo * co - hi * si;
                        v[ni + 2] = hi * co + lo * si;
                    }
                }
                const int h = blockIdx.y;
                unsigned short* dst = (unsigned short*)outp
                    + ((size_t)(b * NHEADS + h) * SEQ + ll) * DHEAD;
                #pragma unroll
                for (int ni = 0; ni < 4; ++ni) dst[ni * 16 + c] = f2bf(v[ni]);
            }
        }
    }
}

// ---------------------------------------------------------------------------
// K4: V [bh][l][64] bf16 -> Vt [bh][64][l] bf16
// ---------------------------------------------------------------------------
__global__ __launch_bounds__(256)
void vtrans_kernel(const unsigned short* __restrict__ V, unsigned short* __restrict__ Vt) {
    __shared__ unsigned short T[64][68];
    const int bh = blockIdx.y, l0 = blockIdx.x * 64;
    const int t = threadIdx.x, r = t >> 4, cq = t & 15;
    const unsigned short* Vb = V + (size_t)bh * SEQ * DHEAD;
    #pragma unroll
    for (int p = 0; p < 4; ++p) {
        int ll = r + 16 * p;
        ushort4 v = *(const ushort4*)&Vb[(size_t)(l0 + ll) * DHEAD + cq * 4];
        T[cq * 4 + 0][ll] = v.x; T[cq * 4 + 1][ll] = v.y;
        T[cq * 4 + 2][ll] = v.z; T[cq * 4 + 3][ll] = v.w;
    }
    __syncthreads();
    unsigned short* Vo = Vt + (size_t)bh * DHEAD * SEQ;
    #pragma unroll
    for (int p = 0; p < 4; ++p) {
        int d = r + 16 * p;
        ushort4 o;
        o.x = T[d][cq * 4 + 0]; o.y = T[d][cq * 4 + 1];
        o.z = T[d][cq * 4 + 2]; o.w = T[d][cq * 4 + 3];
        *(ushort4*)&Vo[(size_t)d * SEQ + l0 + cq * 4] = o;
    }
}

// ---------------------------------------------------------------------------
// K5: MFMA flash attention, 32x32x16 swapped-operand structure.
// QBLK=128 (4 waves x 32 q-rows), KVBLK=64, online softmax.
// S = mfma(K, Q) -> D[k][q]: col=lane&31=q (one q per lane), rows = k.
// Softmax per-lane scalar state (m, l); reductions = 31 in-lane + 1 shfl_xor(32).
// P -> PV B-fragment entirely in registers: per 16-k chunk 4x v_cvt_pk_bf16_f32
// + 2x v_permlane32_swap_b32 (T12). O^T = mfma(V, P): col=q -> scalar rescale.
// K/V double-buffered swizzled LDS via global_load_lds, one barrier per tile.
// ---------------------------------------------------------------------------
__global__ __launch_bounds__(256, 2)
void attn_mfma32_kernel(const unsigned short* __restrict__ Q, const unsigned short* __restrict__ K,
                        const unsigned short* __restrict__ Vt, unsigned short* __restrict__ O)
{
    __shared__ unsigned short Ks[2][64 * 64];
    __shared__ unsigned short Vs[2][64 * 64];
    const int tid = threadIdx.x;
    const int w = tid >> 6, ln = tid & 63;
    const int ql = ln & 31;                 // this lane's q (col of D)
    const int h  = ln >> 5;                 // lane half
    const int bh = blockIdx.y;
    const int q  = blockIdx.x * 128 + w * 32 + ql;   // global q row owned
    const float SC = 0.125f * 1.44269504088896340736f;  // scale * log2(e)
    const int srow = ln >> 3, sblk = ln & 7;

    const unsigned short* Qb = Q  + (size_t)bh * SEQ * DHEAD;
    const unsigned short* Kb = K  + (size_t)bh * SEQ * DHEAD;
    const unsigned short* Vb = Vt + (size_t)bh * DHEAD * SEQ;

    // Q fragments (B-operand): B[j=ql][d = dk*16 + h*8 + s]
    short8 qf[4];
    #pragma unroll
    for (int dk = 0; dk < 4; ++dk)
        qf[dk] = *(const short8*)&Qb[(size_t)q * DHEAD + dk * 16 + h * 8];

    f32x16 accO0, accO1;
    #pragma unroll
    for (int r = 0; r < 16; ++r) { accO0[r] = 0.f; accO1[r] = 0.f; }
    float accL = 0.f, mst = -1e30f;

    // prologue: stage tile 0 into buf 0 (K: 8 chunks, V: 8 chunks; 2+2 per wave)
    #pragma unroll
    for (int i = 0; i < 2; ++i) {
        int chunk = w * 2 + i;
        int row = chunk * 8 + srow;
        int gcol = (sblk ^ (row & 7)) * 8;
        gload_lds16(&Kb[(size_t)row * DHEAD + gcol], &Ks[0][chunk * 512]);
        gload_lds16(&Vb[(size_t)row * SEQ + gcol],   &Vs[0][chunk * 512]);
    }
    __syncthreads();

    int cur = 0;
    for (int kt = 0; kt < SEQ; kt += 64) {
        // stage NEXT tile into buf^1 (in flight during compute)
        if (kt + 64 < SEQ) {
            #pragma unroll
            for (int i = 0; i < 2; ++i) {
                int chunk = w * 2 + i;
                int row = chunk * 8 + srow;
                int gcol = (sblk ^ (row & 7)) * 8;
                gload_lds16(&Kb[(size_t)(kt + 64 + row) * DHEAD + gcol], &Ks[cur ^ 1][chunk * 512]);
                gload_lds16(&Vb[(size_t)row * SEQ + kt + 64 + gcol],     &Vs[cur ^ 1][chunk * 512]);
            }
        }

        // S = K Q^T : s0 = k-rows 0..31, s1 = k-rows 32..63 (cols = q)
        f32x16 s0, s1;
        #pragma unroll
        for (int r = 0; r < 16; ++r) { s0[r] = 0.f; s1[r] = 0.f; }
        #pragma unroll
        for (int dk = 0; dk < 4; ++dk) {
            const int off = ((2 * dk + h) ^ (ql & 7)) * 8;
            short8 kf0 = *(const short8*)&Ks[cur][ql * 64 + off];
            short8 kf1 = *(const short8*)&Ks[cur][(32 + ql) * 64 + off];
            s0 = MFMA32(kf0, qf[dk], s0);
            s1 = MFMA32(kf1, qf[dk], s1);
        }

        // online row max: 31 in-lane + 1 cross-half shfl
        float mx = s0[0];
        #pragma unroll
        for (int r = 1; r < 16; ++r) mx = fmaxf(mx, s0[r]);
        #pragma unroll
        for (int r = 0; r < 16; ++r) mx = fmaxf(mx, s1[r]);
        mx = fmaxf(mx, __shfl_xor(mx, 32));
        const float mn = fmaxf(mst, mx);
        const float rsc = exp2f((mst - mn) * SC);
        mst = mn;

        // P = exp2((S - m)*SC), in place
        #pragma unroll
        for (int r = 0; r < 16; ++r) {
            s0[r] = exp2f((s0[r] - mn) * SC);
            s1[r] = exp2f((s1[r] - mn) * SC);
        }

        // tile row-sum: in-lane + cross-half
        float ts = 0.f;
        #pragma unroll
        for (int r = 0; r < 16; ++r) ts += s0[r] + s1[r];
        ts += __shfl_xor(ts, 32);
        accL = accL * rsc + ts;

        // rescale running O
        #pragma unroll
        for (int r = 0; r < 16; ++r) { accO0[r] *= rsc; accO1[r] *= rsc; }

        // repack P (fp32, D-layout) -> 4 bf16 B-fragments pf[t], k = 16t..16t+15
        // per t: wA(m1) from regs 8(t&1)+2m1 (+1), wB(m1) from regs 8(t&1)+4+2m1 (+1);
        // permlane32_swap(wA,wB) -> words {m1, 2+m1}. All indices static.
        short8 pf[4];
        #define REPACK_T(T, SV)                                                          \
        {                                                                                \
            unsigned int wA0, wA1, wB0, wB1;                                             \
            asm("v_cvt_pk_bf16_f32 %0, %1, %2" : "=v"(wA0)                               \
                : "v"((SV)[8 * ((T) & 1) + 0]), "v"((SV)[8 * ((T) & 1) + 1]));           \
            asm("v_cvt_pk_bf16_f32 %0, %1, %2" : "=v"(wA1)                               \
                : "v"((SV)[8 * ((T) & 1) + 2]), "v"((SV)[8 * ((T) & 1) + 3]));           \
            asm("v_cvt_pk_bf16_f32 %0, %1, %2" : "=v"(wB0)                               \
                : "v"((SV)[8 * ((T) & 1) + 4]), "v"((SV)[8 * ((T) & 1) + 5]));           \
            asm("v_cvt_pk_bf16_f32 %0, %1, %2" : "=v"(wB1)                               \
                : "v"((SV)[8 * ((T) & 1) + 6]), "v"((SV)[8 * ((T) & 1) + 7]));           \
            asm("v_permlane32_swap_b32 %0, %1" : "+v"(wA0), "+v"(wB0));                  \
            asm("v_permlane32_swap_b32 %0, %1" : "+v"(wA1), "+v"(wB1));                  \
            union { short8 v; unsigned int u[4]; } tmp;                                  \
            tmp.u[0] = wA0; tmp.u[1] = wA1; tmp.u[2] = wB0; tmp.u[3] = wB1;              \
            pf[T] = tmp.v;                                                               \
        }
        REPACK_T(0, s0) REPACK_T(1, s0) REPACK_T(2, s1) REPACK_T(3, s1)
        #undef REPACK_T

        // O^T += V^T P : A = V-frag (rows = d), B = pf (cols = q)
        #pragma unroll
        for (int t = 0; t < 4; ++t) {
            const int off = ((2 * t + h) ^ (ql & 7)) * 8;
            short8 vf0 = *(const short8*)&Vs[cur][ql * 64 + off];
            short8 vf1 = *(const short8*)&Vs[cur][(32 + ql) * 64 + off];
            accO0 = MFMA32(vf0, pf[t], accO0);
            accO1 = MFMA32(vf1, pf[t], accO1);
        }

        __syncthreads();   // drains vmcnt (staged tile) + all waves done with buf
        cur ^= 1;
    }

    // epilogue: O[q][d] = accO^T / l, bf16 to [B,L,D]; d = 32dc + 8rq + 4h + j
    const int b = bh >> 4, hh = bh & 15;
    const float inv = 1.0f / accL;
    unsigned short* dst = O + ((size_t)(b * SEQ + q)) * D_MODEL + hh * DHEAD;
    #define EPI(ACC, DC)                                                                 \
    {                                                                                    \
        _Pragma("unroll")                                                                \
        for (int rq = 0; rq < 4; ++rq) {                                                 \
            float a0 = (ACC)[4 * rq + 0] * inv, a1 = (ACC)[4 * rq + 1] * inv;            \
            float a2 = (ACC)[4 * rq + 2] * inv, a3 = (ACC)[4 * rq + 3] * inv;            \
            unsigned int p0, p1;                                                         \
            asm("v_cvt_pk_bf16_f32 %0, %1, %2" : "=v"(p0) : "v"(a0), "v"(a1));           \
            asm("v_cvt_pk_bf16_f32 %0, %1, %2" : "=v"(p1) : "v"(a2), "v"(a3));           \
            uint2 pk; pk.x = p0; pk.y = p1;                                              \
            *(uint2*)(dst + 32 * (DC) + 8 * rq + 4 * h) = pk;                            \
        }                                                                                \
    }
    EPI(accO0, 0) EPI(accO1, 1)
    #undef EPI
}

// ---------------------------------------------------------------------------
extern "C" void kernel_launch(void* const* d_in, const int* in_sizes, int n_in,
                              void* d_out, int out_size, void* d_ws, size_t ws_size,
                              hipStream_t stream)
{
    const float* x  = (const float*)d_in[0];
    const float* Wq = (const float*)d_in[1];
    const float* bq = (const float*)d_in[2];
    const float* Wk = (const float*)d_in[3];
    const float* bk = (const float*)d_in[4];
    const float* Wv = (const float*)d_in[5];
    const float* bv = (const float*)d_in[6];
    const float* Wo = (const float*)d_in[7];
    const float* bo = (const float*)d_in[8];

    float* cosT = (float*)d_ws;
    float* sinT = cosT + SEQ * HALF_DH;
    unsigned short* xb  = (unsigned short*)(sinT + SEQ * HALF_DH);
    unsigned short* wqT = xb  + (size_t)MROWS * D_MODEL;
    unsigned short* wkT = wqT + (size_t)D_MODEL * D_MODEL;
    unsigned short* wvT = wkT + (size_t)D_MODEL * D_MODEL;
    unsigned short* woT = wvT + (size_t)D_MODEL * D_MODEL;
    unsigned short* qb  = woT + (size_t)D_MODEL * D_MODEL;
    unsigned short* kb  = qb  + (size_t)MROWS * D_MODEL;
    unsigned short* vb  = kb  + (size_t)MROWS * D_MODEL;
    unsigned short* vtb = vb  + (size_t)MROWS * D_MODEL;
    unsigned short* ob  = vtb + (size_t)MROWS * D_MODEL;

    rope_table_kernel<<<(SEQ * HALF_DH + 255) / 256, 256, 0, stream>>>(cosT, sinT);
    convert_bf16_kernel<<<(MROWS * D_MODEL / 4) / 256, 256, 0, stream>>>(x, xb);

    dim3 wgrid(D_MODEL / 64, D_MODEL / 64);
    wtrans_kernel<<<wgrid, 256, 0, stream>>>(Wq, wqT);
    wtrans_kernel<<<wgrid, 256, 0, stream>>>(Wk, wkT);
    wtrans_kernel<<<wgrid, 256, 0, stream>>>(Wv, wvT);
    wtrans_kernel<<<wgrid, 256, 0, stream>>>(Wo, woT);

    dim3 pgrid(MROWS / 128, D_MODEL / 64);
    proj_mfma_kernel<0><<<pgrid, 256, 0, stream>>>(xb, wqT, bq, cosT, sinT, qb);
    proj_mfma_kernel<0><<<pgrid, 256, 0, stream>>>(xb, wkT, bk, cosT, sinT, kb);
    proj_mfma_kernel<1><<<pgrid, 256, 0, stream>>>(xb, wvT, bv, cosT, sinT, vb);

    dim3 vgrid(SEQ / 64, BATCH * NHEADS);
    vtrans_kernel<<<vgrid, 256, 0, stream>>>(vb, vtb);

    dim3 agrid(SEQ / 128, BATCH * NHEADS);
    attn_mfma32_kernel<<<agrid, 256, 0, stream>>>(qb, kb, vtb, ob);

    proj_mfma_kernel<2><<<pgrid, 256, 0, stream>>>(ob, woT, bo, cosT, sinT, d_out);
}

// Round 8
// 152.570 us; speedup vs baseline: 8.7598x; 1.1042x over previous
//
#include <hip/hip_runtime.h>
#include <cmath>

#define D_MODEL  1024
#define NHEADS   16
#define DHEAD    64
#define BATCH    2
#define SEQ      2048
#define MROWS    (BATCH * SEQ)
#define HALF_DH  32
#define BHTOT    (BATCH * NHEADS)          // 32
#define QROWS    (BHTOT * SEQ)             // 65536 (bh*2048+q index space)

typedef __attribute__((ext_vector_type(8))) short short8;    // 8 bf16 = 4 VGPRs
typedef __attribute__((ext_vector_type(4))) float f32x4;     // 16x16 C/D
typedef __attribute__((ext_vector_type(16))) float f32x16;   // 32x32 C/D

#define MFMA16(A,B,C) __builtin_amdgcn_mfma_f32_16x16x32_bf16(A,B,C,0,0,0)
#define MFMA32(A,B,C) __builtin_amdgcn_mfma_f32_32x32x16_bf16(A,B,C,0,0,0)

__device__ __forceinline__ unsigned short f2bf(float f) {
    unsigned int u = __float_as_uint(f);
    u += 0x7fffu + ((u >> 16) & 1u);
    return (unsigned short)(u >> 16);
}

__device__ __forceinline__ void gload_lds16(const void* g, void* l) {
    __builtin_amdgcn_global_load_lds(
        (const __attribute__((address_space(1))) unsigned int*)g,
        (__attribute__((address_space(3))) unsigned int*)l,
        16, 0, 0);
}

// ---------------------------------------------------------------------------
// K0: RoPE cos/sin tables [SEQ][32] fp32
// ---------------------------------------------------------------------------
__global__ void rope_table_kernel(float* __restrict__ cosT, float* __restrict__ sinT) {
    int idx = blockIdx.x * blockDim.x + threadIdx.x;
    if (idx >= SEQ * HALF_DH) return;
    int l = idx >> 5;
    int j = idx & 31;
    float inv = powf(10000.0f, -(float)(2 * j) / (float)DHEAD);
    float ang = (float)l * inv;
    cosT[idx] = cosf(ang);
    sinT[idx] = sinf(ang);
}

// ---------------------------------------------------------------------------
// K1: fp32 -> bf16 elementwise (x)
// ---------------------------------------------------------------------------
__global__ __launch_bounds__(256)
void convert_bf16_kernel(const float* __restrict__ in, unsigned short* __restrict__ out) {
    int i = blockIdx.x * 256 + threadIdx.x;
    float4 v = ((const float4*)in)[i];
    ushort4 o;
    o.x = f2bf(v.x); o.y = f2bf(v.y); o.z = f2bf(v.z); o.w = f2bf(v.w);
    ((ushort4*)out)[i] = o;
}

// ---------------------------------------------------------------------------
// K2: all four weights W[k][n] fp32 -> Wt[n][k] bf16, fused via blockIdx.z
// ---------------------------------------------------------------------------
__global__ __launch_bounds__(256)
void wtrans4_kernel(const float* __restrict__ Wq, const float* __restrict__ Wk,
                    const float* __restrict__ Wv, const float* __restrict__ Wo,
                    unsigned short* __restrict__ q, unsigned short* __restrict__ k,
                    unsigned short* __restrict__ v, unsigned short* __restrict__ o)
{
    __shared__ unsigned short T[64][68];
    const float* W; unsigned short* Wt;
    switch (blockIdx.z) {
        case 0:  W = Wq; Wt = q; break;
        case 1:  W = Wk; Wt = k; break;
        case 2:  W = Wv; Wt = v; break;
        default: W = Wo; Wt = o; break;
    }
    const int k0 = blockIdx.x * 64, n0 = blockIdx.y * 64;
    const int t = threadIdx.x, r = t >> 4, cq = t & 15;
    #pragma unroll
    for (int p = 0; p < 4; ++p) {
        int kk = r + 16 * p;
        float4 vv = *(const float4*)&W[(size_t)(k0 + kk) * D_MODEL + n0 + cq * 4];
        T[cq * 4 + 0][kk] = f2bf(vv.x);
        T[cq * 4 + 1][kk] = f2bf(vv.y);
        T[cq * 4 + 2][kk] = f2bf(vv.z);
        T[cq * 4 + 3][kk] = f2bf(vv.w);
    }
    __syncthreads();
    #pragma unroll
    for (int p = 0; p < 4; ++p) {
        int n = r + 16 * p;
        ushort4 ov;
        ov.x = T[n][cq * 4 + 0]; ov.y = T[n][cq * 4 + 1];
        ov.z = T[n][cq * 4 + 2]; ov.w = T[n][cq * 4 + 3];
        *(ushort4*)&Wt[(size_t)(n0 + n) * D_MODEL + k0 + cq * 4] = ov;
    }
}

// ---------------------------------------------------------------------------
// K3: fused QKV projection. blockIdx.z: 0=q (RoPE->[b,h,l,d]), 1=k (same),
// 2=v (LDS-transpose epilogue -> Vt[bh][d][l]).
// ---------------------------------------------------------------------------
__global__ __launch_bounds__(256)
void qkv_proj_kernel(const unsigned short* __restrict__ A,
                     const unsigned short* __restrict__ wqT, const unsigned short* __restrict__ wkT,
                     const unsigned short* __restrict__ wvT,
                     const float* __restrict__ bq, const float* __restrict__ bk,
                     const float* __restrict__ bv,
                     const float* __restrict__ cosT, const float* __restrict__ sinT,
                     unsigned short* __restrict__ qb, unsigned short* __restrict__ kb,
                     unsigned short* __restrict__ vtb)
{
    __shared__ unsigned short SMEM[128 * 64 + 64 * 64];   // As(16KB) + Bs(8KB)
    unsigned short* As = SMEM;
    unsigned short* Bs = SMEM + 128 * 64;

    const int z = blockIdx.z;
    const unsigned short* Bt = (z == 0) ? wqT : (z == 1) ? wkT : wvT;
    const float* bias = (z == 0) ? bq : (z == 1) ? bk : bv;

    const int tid = threadIdx.x;
    const int w = tid >> 6, ln = tid & 63;
    const int c = ln & 15, g = ln >> 4;
    const int bm = blockIdx.x * 128, bn = blockIdx.y * 64;
    const int srow = ln >> 3, sblk = ln & 7;

    f32x4 acc[2][4];
    #pragma unroll
    for (int mi = 0; mi < 2; ++mi)
        #pragma unroll
        for (int ni = 0; ni < 4; ++ni) acc[mi][ni] = (f32x4){0.f, 0.f, 0.f, 0.f};

    for (int k0 = 0; k0 < D_MODEL; k0 += 64) {
        __syncthreads();
        #pragma unroll
        for (int i = 0; i < 4; ++i) {
            int chunk = w * 4 + i;
            int row = chunk * 8 + srow;
            int gcol = (sblk ^ (row & 7)) * 8;
            gload_lds16(&A[(size_t)(bm + row) * D_MODEL + k0 + gcol], &As[chunk * 512]);
        }
        #pragma unroll
        for (int i = 0; i < 2; ++i) {
            int chunk = w * 2 + i;
            int row = chunk * 8 + srow;
            int gcol = (sblk ^ (row & 7)) * 8;
            gload_lds16(&Bt[(size_t)(bn + row) * D_MODEL + k0 + gcol], &Bs[chunk * 512]);
        }
        __syncthreads();

        #pragma unroll
        for (int ks = 0; ks < 2; ++ks) {
            const int koff = (ks * 32 + g * 8) ^ ((c & 7) * 8);
            short8 af[2];
            #pragma unroll
            for (int mi = 0; mi < 2; ++mi)
                af[mi] = *(const short8*)&As[(w * 32 + mi * 16 + c) * 64 + koff];
            #pragma unroll
            for (int ni = 0; ni < 4; ++ni) {
                short8 bfr = *(const short8*)&Bs[(ni * 16 + c) * 64 + koff];
                #pragma unroll
                for (int mi = 0; mi < 2; ++mi)
                    acc[mi][ni] = MFMA16(af[mi], bfr, acc[mi][ni]);
            }
        }
    }

    float bv4[4];
    #pragma unroll
    for (int ni = 0; ni < 4; ++ni) bv4[ni] = bias[bn + ni * 16 + c];

    if (z < 2) {
        unsigned short* op = z ? kb : qb;
        const int hy = blockIdx.y;                    // head (BN == DHEAD)
        #pragma unroll
        for (int mi = 0; mi < 2; ++mi) {
            #pragma unroll
            for (int r = 0; r < 4; ++r) {
                const int m = bm + w * 32 + mi * 16 + g * 4 + r;
                const int b = m >> 11, ll = m & (SEQ - 1);
                float v[4];
                #pragma unroll
                for (int ni = 0; ni < 4; ++ni) v[ni] = acc[mi][ni][r] + bv4[ni];
                #pragma unroll
                for (int ni = 0; ni < 2; ++ni) {      // RoPE
                    int d = ni * 16 + c;
                    float co = cosT[ll * HALF_DH + d];
                    float si = sinT[ll * HALF_DH + d];
                    float lo = v[ni], hi = v[ni + 2];
                    v[ni]     = lo * co - hi * si;
                    v[ni + 2] = hi * co + lo * si;
                }
                unsigned short* dst = op + ((size_t)(b * NHEADS + hy) * SEQ + ll) * DHEAD;
                #pragma unroll
                for (int ni = 0; ni < 4; ++ni) dst[ni * 16 + c] = f2bf(v[ni]);
            }
        }
    } else {
        // v: transpose 128(m) x 64(d) tile -> Vt[bh][d][l] via LDS (overlay SMEM)
        unsigned short (*T)[136] = (unsigned short(*)[136])SMEM;   // 64 x 136 shorts
        __syncthreads();                               // all MFMA LDS reads done
        #pragma unroll
        for (int mi = 0; mi < 2; ++mi)
            #pragma unroll
            for (int r = 0; r < 4; ++r)
                #pragma unroll
                for (int ni = 0; ni < 4; ++ni)
                    T[ni * 16 + c][w * 32 + mi * 16 + g * 4 + r] = f2bf(acc[mi][ni][r] + bv4[ni]);
        __syncthreads();
        const int b  = bm >> 11;
        const int l0 = bm & (SEQ - 1);                 // FIX (R7 bug): per-batch seq offset
        const int bh = b * NHEADS + blockIdx.y;
        unsigned short* Vo = vtb + (size_t)bh * DHEAD * SEQ;
        #pragma unroll
        for (int it = 0; it < 4; ++it) {
            int row  = (tid >> 4) + it * 16;           // d
            int col8 = tid & 15;                       // 8-short chunk along m
            uint4 val = *(const uint4*)&T[row][col8 * 8];
            *(uint4*)&Vo[(size_t)row * SEQ + l0 + col8 * 8] = val;
        }
    }
}

// ---------------------------------------------------------------------------
// K4: out-projection GEMM (bf16 A=ob, fp32 out)
// ---------------------------------------------------------------------------
__global__ __launch_bounds__(256)
void outproj_kernel(const unsigned short* __restrict__ A, const unsigned short* __restrict__ Bt,
                    const float* __restrict__ bias, float* __restrict__ out)
{
    __shared__ unsigned short As[128 * 64];
    __shared__ unsigned short Bs[64 * 64];
    const int tid = threadIdx.x;
    const int w = tid >> 6, ln = tid & 63;
    const int c = ln & 15, g = ln >> 4;
    const int bm = blockIdx.x * 128, bn = blockIdx.y * 64;
    const int srow = ln >> 3, sblk = ln & 7;

    f32x4 acc[2][4];
    #pragma unroll
    for (int mi = 0; mi < 2; ++mi)
        #pragma unroll
        for (int ni = 0; ni < 4; ++ni) acc[mi][ni] = (f32x4){0.f, 0.f, 0.f, 0.f};

    for (int k0 = 0; k0 < D_MODEL; k0 += 64) {
        __syncthreads();
        #pragma unroll
        for (int i = 0; i < 4; ++i) {
            int chunk = w * 4 + i;
            int row = chunk * 8 + srow;
            int gcol = (sblk ^ (row & 7)) * 8;
            gload_lds16(&A[(size_t)(bm + row) * D_MODEL + k0 + gcol], &As[chunk * 512]);
        }
        #pragma unroll
        for (int i = 0; i < 2; ++i) {
            int chunk = w * 2 + i;
            int row = chunk * 8 + srow;
            int gcol = (sblk ^ (row & 7)) * 8;
            gload_lds16(&Bt[(size_t)(bn + row) * D_MODEL + k0 + gcol], &Bs[chunk * 512]);
        }
        __syncthreads();

        #pragma unroll
        for (int ks = 0; ks < 2; ++ks) {
            const int koff = (ks * 32 + g * 8) ^ ((c & 7) * 8);
            short8 af[2];
            #pragma unroll
            for (int mi = 0; mi < 2; ++mi)
                af[mi] = *(const short8*)&As[(w * 32 + mi * 16 + c) * 64 + koff];
            #pragma unroll
            for (int ni = 0; ni < 4; ++ni) {
                short8 bfr = *(const short8*)&Bs[(ni * 16 + c) * 64 + koff];
                #pragma unroll
                for (int mi = 0; mi < 2; ++mi)
                    acc[mi][ni] = MFMA16(af[mi], bfr, acc[mi][ni]);
            }
        }
    }

    float bv4[4];
    #pragma unroll
    for (int ni = 0; ni < 4; ++ni) bv4[ni] = bias[bn + ni * 16 + c];
    #pragma unroll
    for (int mi = 0; mi < 2; ++mi)
        #pragma unroll
        for (int r = 0; r < 4; ++r) {
            const int m = bm + w * 32 + mi * 16 + g * 4 + r;
            #pragma unroll
            for (int ni = 0; ni < 4; ++ni)
                out[(size_t)m * D_MODEL + bn + ni * 16 + c] = acc[mi][ni][r] + bv4[ni];
        }
}

// ---------------------------------------------------------------------------
// K5: MFMA flash attention, 32x32 swapped-operand, split-K over KV (grid.z).
// nsplit==1: write final bf16 O. nsplit==2: store partials (accO fp32, m, l);
// combine2_kernel merges. Tree reductions; exact rescale-skip via __any.
// ---------------------------------------------------------------------------
__global__ __launch_bounds__(256, 4)
void attn_mfma32_kernel(const unsigned short* __restrict__ Q, const unsigned short* __restrict__ K,
                        const unsigned short* __restrict__ Vt, unsigned short* __restrict__ O,
                        float* __restrict__ accP, float* __restrict__ ml, int nsplit)
{
    __shared__ unsigned short Ks[2][64 * 64];
    __shared__ unsigned short Vs[2][64 * 64];
    const int tid = threadIdx.x;
    const int w = tid >> 6, ln = tid & 63;
    const int ql = ln & 31;
    const int h  = ln >> 5;
    const int bh = blockIdx.y;
    const int q  = blockIdx.x * 128 + w * 32 + ql;
    const int split = blockIdx.z;
    const int ntile = SEQ / (64 * nsplit);
    const int kt0 = split * (SEQ / nsplit);
    const float SC = 0.125f * 1.44269504088896340736f;
    const int srow = ln >> 3, sblk = ln & 7;

    const unsigned short* Qb = Q  + (size_t)bh * SEQ * DHEAD;
    const unsigned short* Kb = K  + (size_t)bh * SEQ * DHEAD;
    const unsigned short* Vb = Vt + (size_t)bh * DHEAD * SEQ;

    short8 qf[4];
    #pragma unroll
    for (int dk = 0; dk < 4; ++dk)
        qf[dk] = *(const short8*)&Qb[(size_t)q * DHEAD + dk * 16 + h * 8];

    f32x16 accO0, accO1;
    #pragma unroll
    for (int r = 0; r < 16; ++r) { accO0[r] = 0.f; accO1[r] = 0.f; }
    float accL = 0.f, mst = -1e30f;

    // prologue: stage first tile of this split
    #pragma unroll
    for (int i = 0; i < 2; ++i) {
        int chunk = w * 2 + i;
        int row = chunk * 8 + srow;
        int gcol = (sblk ^ (row & 7)) * 8;
        gload_lds16(&Kb[(size_t)(kt0 + row) * DHEAD + gcol], &Ks[0][chunk * 512]);
        gload_lds16(&Vb[(size_t)row * SEQ + kt0 + gcol],     &Vs[0][chunk * 512]);
    }
    __syncthreads();

    int cur = 0;
    for (int it = 0; it < ntile; ++it) {
        const int kt = kt0 + it * 64;
        if (it + 1 < ntile) {
            #pragma unroll
            for (int i = 0; i < 2; ++i) {
                int chunk = w * 2 + i;
                int row = chunk * 8 + srow;
                int gcol = (sblk ^ (row & 7)) * 8;
                gload_lds16(&Kb[(size_t)(kt + 64 + row) * DHEAD + gcol], &Ks[cur ^ 1][chunk * 512]);
                gload_lds16(&Vb[(size_t)row * SEQ + kt + 64 + gcol],     &Vs[cur ^ 1][chunk * 512]);
            }
        }

        // S = K Q^T
        f32x16 s0, s1;
        #pragma unroll
        for (int r = 0; r < 16; ++r) { s0[r] = 0.f; s1[r] = 0.f; }
        #pragma unroll
        for (int dk = 0; dk < 4; ++dk) {
            const int off = ((2 * dk + h) ^ (ql & 7)) * 8;
            short8 kf0 = *(const short8*)&Ks[cur][ql * 64 + off];
            short8 kf1 = *(const short8*)&Ks[cur][(32 + ql) * 64 + off];
            s0 = MFMA32(kf0, qf[dk], s0);
            s1 = MFMA32(kf1, qf[dk], s1);
        }

        // row max: pairwise tree (depth 5) + one cross-half shfl
        float m16[16];
        #pragma unroll
        for (int r = 0; r < 16; ++r) m16[r] = fmaxf(s0[r], s1[r]);
        #pragma unroll
        for (int st = 8; st >= 1; st >>= 1)
            #pragma unroll
            for (int r = 0; r < st; ++r) m16[r] = fmaxf(m16[r], m16[r + st]);
        float mx = m16[0];
        mx = fmaxf(mx, __shfl_xor(mx, 32));

        // exact skip: rescale only if some lane's max grew
        const float mn = fmaxf(mst, mx);
        if (__any(mn > mst)) {
            const float rsc = exp2f((mst - mn) * SC);
            #pragma unroll
            for (int r = 0; r < 16; ++r) { accO0[r] *= rsc; accO1[r] *= rsc; }
            accL *= rsc;
            mst = mn;
        }

        // P = exp2((S - m)*SC)
        #pragma unroll
        for (int r = 0; r < 16; ++r) {
            s0[r] = exp2f((s0[r] - mst) * SC);
            s1[r] = exp2f((s1[r] - mst) * SC);
        }

        // tile row-sum: pairwise tree + cross-half
        float t16[16];
        #pragma unroll
        for (int r = 0; r < 16; ++r) t16[r] = s0[r] + s1[r];
        #pragma unroll
        for (int st = 8; st >= 1; st >>= 1)
            #pragma unroll
            for (int r = 0; r < st; ++r) t16[r] += t16[r + st];
        float ts = t16[0];
        ts += __shfl_xor(ts, 32);
        accL += ts;

        // repack P -> 4 bf16 B-fragments (cvt_pk + permlane32_swap, verified R5)
        short8 pf[4];
        #define REPACK_T(T, SV)                                                          \
        {                                                                                \
            unsigned int wA0, wA1, wB0, wB1;                                             \
            asm("v_cvt_pk_bf16_f32 %0, %1, %2" : "=v"(wA0)                               \
                : "v"((SV)[8 * ((T) & 1) + 0]), "v"((SV)[8 * ((T) & 1) + 1]));           \
            asm("v_cvt_pk_bf16_f32 %0, %1, %2" : "=v"(wA1)                               \
                : "v"((SV)[8 * ((T) & 1) + 2]), "v"((SV)[8 * ((T) & 1) + 3]));           \
            asm("v_cvt_pk_bf16_f32 %0, %1, %2" : "=v"(wB0)                               \
                : "v"((SV)[8 * ((T) & 1) + 4]), "v"((SV)[8 * ((T) & 1) + 5]));           \
            asm("v_cvt_pk_bf16_f32 %0, %1, %2" : "=v"(wB1)                               \
                : "v"((SV)[8 * ((T) & 1) + 6]), "v"((SV)[8 * ((T) & 1) + 7]));           \
            asm("v_permlane32_swap_b32 %0, %1" : "+v"(wA0), "+v"(wB0));                  \
            asm("v_permlane32_swap_b32 %0, %1" : "+v"(wA1), "+v"(wB1));                  \
            union { short8 v; unsigned int u[4]; } tmp;                                  \
            tmp.u[0] = wA0; tmp.u[1] = wA1; tmp.u[2] = wB0; tmp.u[3] = wB1;              \
            pf[T] = tmp.v;                                                               \
        }
        REPACK_T(0, s0) REPACK_T(1, s0) REPACK_T(2, s1) REPACK_T(3, s1)
        #undef REPACK_T

        // O^T += V^T P
        #pragma unroll
        for (int t = 0; t < 4; ++t) {
            const int off = ((2 * t + h) ^ (ql & 7)) * 8;
            short8 vf0 = *(const short8*)&Vs[cur][ql * 64 + off];
            short8 vf1 = *(const short8*)&Vs[cur][(32 + ql) * 64 + off];
            accO0 = MFMA32(vf0, pf[t], accO0);
            accO1 = MFMA32(vf1, pf[t], accO1);
        }

        __syncthreads();
        cur ^= 1;
    }

    if (nsplit == 1) {
        const int b = bh >> 4, hh = bh & 15;
        const float inv = 1.0f / accL;
        unsigned short* dst = O + ((size_t)(b * SEQ + q)) * D_MODEL + hh * DHEAD;
        #define EPI(ACC, DC)                                                             \
        {                                                                                \
            _Pragma("unroll")                                                            \
            for (int rq = 0; rq < 4; ++rq) {                                             \
                float a0 = (ACC)[4 * rq + 0] * inv, a1 = (ACC)[4 * rq + 1] * inv;        \
                float a2 = (ACC)[4 * rq + 2] * inv, a3 = (ACC)[4 * rq + 3] * inv;        \
                unsigned int p0, p1;                                                     \
                asm("v_cvt_pk_bf16_f32 %0, %1, %2" : "=v"(p0) : "v"(a0), "v"(a1));       \
                asm("v_cvt_pk_bf16_f32 %0, %1, %2" : "=v"(p1) : "v"(a2), "v"(a3));       \
                uint2 pk; pk.x = p0; pk.y = p1;                                          \
                *(uint2*)(dst + 32 * (DC) + 8 * rq + 4 * h) = pk;                        \
            }                                                                            \
        }
        EPI(accO0, 0) EPI(accO1, 1)
        #undef EPI
    } else {
        // store partials: accO (unnormalized fp32, at max mst), m, l
        float* base = accP + ((size_t)(split * BHTOT + bh) * SEQ + q) * 64;
        #pragma unroll
        for (int rq = 0; rq < 4; ++rq) {
            float4 v0, v1;
            v0.x = accO0[4 * rq + 0]; v0.y = accO0[4 * rq + 1];
            v0.z = accO0[4 * rq + 2]; v0.w = accO0[4 * rq + 3];
            v1.x = accO1[4 * rq + 0]; v1.y = accO1[4 * rq + 1];
            v1.z = accO1[4 * rq + 2]; v1.w = accO1[4 * rq + 3];
            *(float4*)&base[8 * rq + 4 * h]      = v0;
            *(float4*)&base[32 + 8 * rq + 4 * h] = v1;
        }
        if (h == 0) {
            float2 v; v.x = mst; v.y = accL;
            ((float2*)ml)[(size_t)(split * BHTOT + bh) * SEQ + q] = v;
        }
    }
}

// ---------------------------------------------------------------------------
// K6: combine the 2 split-K partials: O = sum_s w_s accO_s / sum_s w_s l_s,
// w_s = exp2((m_s - M)*SC). Exact online-softmax merge in fp32.
// ---------------------------------------------------------------------------
__global__ __launch_bounds__(256)
void combine2_kernel(const float* __restrict__ accP, const float* __restrict__ ml,
                     unsigned short* __restrict__ ob)
{
    const float SC = 0.125f * 1.44269504088896340736f;
    int t = blockIdx.x * 256 + threadIdx.x;        // over QROWS*16
    int d4  = (t & 15) * 4;
    int bhq = t >> 4;
    const float2* ML = (const float2*)ml;
    float2 m0 = ML[bhq];
    float2 m1 = ML[(size_t)QROWS + bhq];
    float M  = fmaxf(m0.x, m1.x);
    float w0 = exp2f((m0.x - M) * SC);
    float w1 = exp2f((m1.x - M) * SC);
    float inv = 1.0f / (w0 * m0.y + w1 * m1.y);
    float4 a0 = *(const float4*)&accP[(size_t)bhq * 64 + d4];
    float4 a1 = *(const float4*)&accP[(size_t)QROWS * 64 + (size_t)bhq * 64 + d4];
    float o0 = (a0.x * w0 + a1.x * w1) * inv;
    float o1 = (a0.y * w0 + a1.y * w1) * inv;
    float o2 = (a0.z * w0 + a1.z * w1) * inv;
    float o3 = (a0.w * w0 + a1.w * w1) * inv;
    int bh = bhq >> 11, q = bhq & (SEQ - 1);
    int b = bh >> 4, hh = bh & 15;
    ushort4 ov;
    ov.x = f2bf(o0); ov.y = f2bf(o1); ov.z = f2bf(o2); ov.w = f2bf(o3);
    *(ushort4*)&ob[((size_t)(b * SEQ + q)) * D_MODEL + hh * DHEAD + d4] = ov;
}

// ---------------------------------------------------------------------------
extern "C" void kernel_launch(void* const* d_in, const int* in_sizes, int n_in,
                              void* d_out, int out_size, void* d_ws, size_t ws_size,
                              hipStream_t stream)
{
    const float* x  = (const float*)d_in[0];
    const float* Wq = (const float*)d_in[1];
    const float* bq = (const float*)d_in[2];
    const float* Wk = (const float*)d_in[3];
    const float* bk = (const float*)d_in[4];
    const float* Wv = (const float*)d_in[5];
    const float* bv = (const float*)d_in[6];
    const float* Wo = (const float*)d_in[7];
    const float* bo = (const float*)d_in[8];

    // workspace carve
    char* p = (char*)d_ws;
    float* cosT = (float*)p;            p += (size_t)SEQ * HALF_DH * 4;
    float* sinT = (float*)p;            p += (size_t)SEQ * HALF_DH * 4;
    unsigned short* xb  = (unsigned short*)p; p += (size_t)MROWS * D_MODEL * 2;
    unsigned short* wqT = (unsigned short*)p; p += (size_t)D_MODEL * D_MODEL * 2;
    unsigned short* wkT = (unsigned short*)p; p += (size_t)D_MODEL * D_MODEL * 2;
    unsigned short* wvT = (unsigned short*)p; p += (size_t)D_MODEL * D_MODEL * 2;
    unsigned short* woT = (unsigned short*)p; p += (size_t)D_MODEL * D_MODEL * 2;
    unsigned short* qb  = (unsigned short*)p; p += (size_t)MROWS * D_MODEL * 2;
    unsigned short* kb  = (unsigned short*)p; p += (size_t)MROWS * D_MODEL * 2;
    unsigned short* vtb = (unsigned short*)p; p += (size_t)MROWS * D_MODEL * 2;
    unsigned short* ob  = (unsigned short*)p; p += (size_t)MROWS * D_MODEL * 2;
    float* accP = (float*)p;            p += (size_t)2 * QROWS * 64 * 4;   // 33.6 MB
    float* ml   = (float*)p;            p += (size_t)2 * QROWS * 2 * 4;    // 1 MB
    size_t need2 = (size_t)(p - (char*)d_ws);
    const int nsplit = (ws_size >= need2) ? 2 : 1;

    rope_table_kernel<<<(SEQ * HALF_DH + 255) / 256, 256, 0, stream>>>(cosT, sinT);
    convert_bf16_kernel<<<(MROWS * D_MODEL / 4) / 256, 256, 0, stream>>>(x, xb);

    wtrans4_kernel<<<dim3(D_MODEL / 64, D_MODEL / 64, 4), 256, 0, stream>>>(
        Wq, Wk, Wv, Wo, wqT, wkT, wvT, woT);

    qkv_proj_kernel<<<dim3(MROWS / 128, D_MODEL / 64, 3), 256, 0, stream>>>(
        xb, wqT, wkT, wvT, bq, bk, bv, cosT, sinT, qb, kb, vtb);

    attn_mfma32_kernel<<<dim3(SEQ / 128, BHTOT, nsplit), 256, 0, stream>>>(
        qb, kb, vtb, ob, accP, ml, nsplit);

    if (nsplit == 2)
        combine2_kernel<<<(QROWS * 16) / 256, 256, 0, stream>>>(accP, ml, ob);

    outproj_kernel<<<dim3(MROWS / 128, D_MODEL / 64), 256, 0, stream>>>(ob, woT, bo, (float*)d_out);
}